// Round 8
// baseline (451.468 us; speedup 1.0000x reference)
//
#include <hip/hip_runtime.h>
#include <hip/hip_bf16.h>
#include <math.h>

#define N_NODES 10000
#define N_EDGES 160000
#define E_TOT   (N_EDGES + N_NODES)
#define F_IN    300
#define D       1024
#define N_CLS   10
#define NEG_SLOPE 0.2f

#define MP      10112              // 79 * 128, padded M
#define KP1     320                // F_IN padded to mult of 32
#define KP2     1024

typedef __attribute__((ext_vector_type(8))) short bf16x8;
typedef __attribute__((ext_vector_type(4))) float f32x4;

#define GLOAD_LDS16(g, l) __builtin_amdgcn_global_load_lds( \
    (const __attribute__((address_space(1))) void*)(g), \
    (__attribute__((address_space(3))) void*)(l), 16, 0, 0)

// ---------------- CSR build ----------------

__global__ void init_deg(int* __restrict__ deg) {
    int i = blockIdx.x * blockDim.x + threadIdx.x;
    if (i < N_NODES) deg[i] = 1;  // self loop
}

__global__ void count_edges(const int* __restrict__ dst, int* __restrict__ deg) {
    int e = blockIdx.x * blockDim.x + threadIdx.x;
    if (e < N_EDGES) atomicAdd(&deg[dst[e]], 1);
}

__global__ void scan_offs(const int* __restrict__ deg, int* __restrict__ offs,
                          int* __restrict__ pos) {
    __shared__ int sbuf[1024];
    __shared__ int scarry;
    int t = threadIdx.x;
    if (t == 0) { scarry = 0; offs[0] = 0; }
    __syncthreads();
    for (int base = 0; base < N_NODES; base += 1024) {
        int v = (base + t < N_NODES) ? deg[base + t] : 0;
        sbuf[t] = v;
        __syncthreads();
        for (int off = 1; off < 1024; off <<= 1) {
            int add = (t >= off) ? sbuf[t - off] : 0;
            __syncthreads();
            sbuf[t] += add;
            __syncthreads();
        }
        int carry = scarry;
        if (base + t < N_NODES) {
            int incl = carry + sbuf[t];
            offs[base + t + 1] = incl;
            pos[base + t]      = incl - v;
        }
        __syncthreads();
        if (t == 1023) scarry = carry + sbuf[1023];
        __syncthreads();
    }
}

__global__ void scatter_edges(const int* __restrict__ src, const int* __restrict__ dst,
                              int* __restrict__ pos, int* __restrict__ ssrc) {
    int e = blockIdx.x * blockDim.x + threadIdx.x;
    if (e < N_EDGES) {
        int d = dst[e];
        int p = atomicAdd(&pos[d], 1);
        ssrc[p] = src[e];
    } else if (e < E_TOT) {
        int i = e - N_EDGES;
        int p = atomicAdd(&pos[i], 1);
        ssrc[p] = i;
    }
}

// ---------------- projected attention vectors: u = W @ a_src, v = W @ a_dst ----------------

__global__ void prep_uv(const float* __restrict__ W1, const float* __restrict__ as1,
                        const float* __restrict__ ad1, const float* __restrict__ W2,
                        const float* __restrict__ as2, const float* __restrict__ ad2,
                        float* __restrict__ u1, float* __restrict__ v1,
                        float* __restrict__ u2, float* __restrict__ v2) {
    int wid  = (int)((blockIdx.x * blockDim.x + threadIdx.x) >> 6);
    int lane = threadIdx.x & 63;
    const float* row;
    const float* a;
    const float* b;
    float *du, *dv;
    int k;
    if (wid < F_IN) {
        k = wid; row = W1 + (size_t)k * D; a = as1; b = ad1; du = u1; dv = v1;
    } else if (wid < F_IN + D) {
        k = wid - F_IN; row = W2 + (size_t)k * D; a = as2; b = ad2; du = u2; dv = v2;
    } else return;
    float s1 = 0.f, s2 = 0.f;
    for (int n = lane; n < D; n += 64) {
        float w = row[n];
        s1 += w * a[n];
        s2 += w * b[n];
    }
    #pragma unroll
    for (int o = 32; o; o >>= 1) { s1 += __shfl_xor(s1, o); s2 += __shfl_xor(s2, o); }
    if (lane == 0) { du[k] = s1; dv[k] = s2; }
}

// ---------------- layer-1 node scores: hs1[i] = x_i . u1, hd1[i] = x_i . v1 ----------------

__global__ void node_scores_x(const float* __restrict__ x, const float* __restrict__ u1,
                              const float* __restrict__ v1, float* __restrict__ hs,
                              float* __restrict__ hd) {
    int wid  = (int)((blockIdx.x * blockDim.x + threadIdx.x) >> 6);
    int lane = threadIdx.x & 63;
    if (wid >= N_NODES) return;
    const float* row = x + (size_t)wid * F_IN;
    float s1 = 0.f, s2 = 0.f;
    for (int k = lane; k < F_IN; k += 64) {
        float v = row[k];
        s1 += v * u1[k];
        s2 += v * v1[k];
    }
    #pragma unroll
    for (int o = 32; o; o >>= 1) { s1 += __shfl_xor(s1, o); s2 += __shfl_xor(s2, o); }
    if (lane == 0) { hs[wid] = s1; hd[wid] = s2; }
}

// ---------------- per-node softmax stats: stats[i] = {max, 1/sum} ----------------

__global__ void seg_stats(const float* __restrict__ hs, const float* __restrict__ hd,
                          const int* __restrict__ offs, const int* __restrict__ ssrc,
                          float* __restrict__ stats) {
    int wid  = (int)((blockIdx.x * blockDim.x + threadIdx.x) >> 6);
    int lane = threadIdx.x & 63;
    if (wid >= N_NODES) return;
    int start = offs[wid], end = offs[wid + 1];
    float hdi = hd[wid];
    float lm = -INFINITY;
    for (int p = start + lane; p < end; p += 64) {
        float s = hs[ssrc[p]] + hdi;
        s = (s >= 0.f) ? s : s * NEG_SLOPE;
        lm = fmaxf(lm, s);
    }
    #pragma unroll
    for (int o = 32; o; o >>= 1) lm = fmaxf(lm, __shfl_xor(lm, o));
    float ls = 0.f;
    for (int p = start + lane; p < end; p += 64) {
        float s = hs[ssrc[p]] + hdi;
        s = (s >= 0.f) ? s : s * NEG_SLOPE;
        ls += __expf(s - lm);
    }
    #pragma unroll
    for (int o = 32; o; o >>= 1) ls += __shfl_xor(ls, o);
    if (lane == 0) {
        float2 st = {lm, 1.0f / ls};
        *(float2*)(stats + 2 * wid) = st;
    }
}

// ---------------- zero hs2/hd2 + pad regions of the A-split buffers ----------------

#define ZR1 (112 * KP1)        // asplit1 pad rows, per buffer
#define ZR2 (N_NODES * 20)     // asplit1 pad cols (300..319), per buffer
#define ZR3 (112 * KP2)        // asplit2 pad rows, per buffer
#define ZTOT (2*ZR1 + 2*ZR2 + 2*ZR3 + 2*N_NODES)

__global__ void zero_misc(float* __restrict__ hs2, float* __restrict__ hd2,
                          __hip_bfloat16* __restrict__ Ah1, __hip_bfloat16* __restrict__ Al1,
                          __hip_bfloat16* __restrict__ Ah2, __hip_bfloat16* __restrict__ Al2) {
    int idx = blockIdx.x * blockDim.x + threadIdx.x;
    if (idx >= ZTOT) return;
    unsigned short z = 0;
    if (idx < 2 * ZR1) {
        __hip_bfloat16* B = (idx < ZR1) ? Ah1 : Al1;
        int off = (idx < ZR1) ? idx : idx - ZR1;
        ((unsigned short*)B)[(size_t)N_NODES * KP1 + off] = z;
    } else if ((idx -= 2 * ZR1) < 2 * ZR2) {
        __hip_bfloat16* B = (idx < ZR2) ? Ah1 : Al1;
        int off = (idx < ZR2) ? idx : idx - ZR2;
        int r = off / 20, c = 300 + off % 20;
        ((unsigned short*)B)[(size_t)r * KP1 + c] = z;
    } else if ((idx -= 2 * ZR2) < 2 * ZR3) {
        __hip_bfloat16* B = (idx < ZR3) ? Ah2 : Al2;
        int off = (idx < ZR3) ? idx : idx - ZR3;
        ((unsigned short*)B)[(size_t)N_NODES * KP2 + off] = z;
    } else {
        idx -= 2 * ZR3;
        if (idx < N_NODES) hs2[idx] = 0.f;
        else hd2[idx - N_NODES] = 0.f;
    }
}

// ---------------- transpose + hi/lo split of W [K][N] -> BT [N][Kp] ----------------

__global__ void transpose_split(const float* __restrict__ W, __hip_bfloat16* __restrict__ BTh,
                                __hip_bfloat16* __restrict__ BTl, int K, int N, int Kp) {
    __shared__ float tile[32][33];
    int k0 = blockIdx.x * 32, n0 = blockIdx.y * 32;
    int tx = threadIdx.x, ty = threadIdx.y;
    #pragma unroll
    for (int j = 0; j < 32; j += 8) {
        int k = k0 + ty + j;
        tile[ty + j][tx] = (k < K) ? W[(size_t)k * N + n0 + tx] : 0.f;
    }
    __syncthreads();
    #pragma unroll
    for (int j = 0; j < 32; j += 8) {
        int n = n0 + ty + j;
        int k = k0 + tx;
        float v = tile[tx][ty + j];
        __hip_bfloat16 hi = __float2bfloat16(v);
        float r = v - __bfloat162float(hi);
        BTh[(size_t)n * Kp + k] = hi;
        BTl[(size_t)n * Kp + k] = __float2bfloat16(r);
    }
}

// ---------------- layer-1 aggregate over raw x, column-sliced (XCD-affine) ----------------
// block (dst, slice): slice = blockIdx&7 handles cols [slice*40, slice*40+40).
// Per-XCD working set: 10000 x 160 B = 1.5 MB -> L2-resident.
// 25 edge-groups x 10 float4 slots; LDS cross-group reduce.

__global__ __launch_bounds__(256) void aggregate_x_slice(
        const float* __restrict__ x, const float* __restrict__ hs,
        const float* __restrict__ hd, const float* __restrict__ stats,
        const int* __restrict__ offs, const int* __restrict__ ssrc,
        __hip_bfloat16* __restrict__ outh, __hip_bfloat16* __restrict__ outl) {
    int bid = blockIdx.x;
    int dst = bid >> 3, slice = bid & 7;
    int t = threadIdx.x;
    int g = t / 10, s = t - g * 10;       // 25 groups x 10 slots (t < 250)
    int c = slice * 40 + s * 4;
    int start = offs[dst], end = offs[dst + 1];
    float2 st = *(const float2*)(stats + 2 * dst);
    float m = st.x, inv = st.y;
    float hdi = hd[dst];
    __shared__ float part[24][10][4];

    float4 a = {0.f, 0.f, 0.f, 0.f};
    if (t < 250 && c < F_IN) {
        for (int p = start + g; p < end; p += 25) {
            int j = ssrc[p];
            float sc = hs[j] + hdi; sc = (sc >= 0.f) ? sc : sc * NEG_SLOPE;
            float w = __expf(sc - m);
            float4 v = *(const float4*)(x + (size_t)j * F_IN + c);
            a.x += w * v.x; a.y += w * v.y; a.z += w * v.z; a.w += w * v.w;
        }
    }
    if (t < 250 && g > 0) {
        part[g - 1][s][0] = a.x; part[g - 1][s][1] = a.y;
        part[g - 1][s][2] = a.z; part[g - 1][s][3] = a.w;
    }
    __syncthreads();
    if (t < 10) {
        int cc = slice * 40 + t * 4;
        float rv[4] = {0.f, 0.f, 0.f, 0.f};
        if (cc < F_IN) {
            #pragma unroll
            for (int q = 0; q < 24; ++q) {
                a.x += part[q][t][0]; a.y += part[q][t][1];
                a.z += part[q][t][2]; a.w += part[q][t][3];
            }
            rv[0] = a.x * inv; rv[1] = a.y * inv; rv[2] = a.z * inv; rv[3] = a.w * inv;
        }
        __hip_bfloat16 hi4[4], lo4[4];
        #pragma unroll
        for (int q = 0; q < 4; ++q) {
            __hip_bfloat16 hi = __float2bfloat16(rv[q]);
            hi4[q] = hi;
            lo4[q] = __float2bfloat16(rv[q] - __bfloat162float(hi));
        }
        *(float2*)(outh + (size_t)dst * KP1 + cc) = *(float2*)hi4;
        *(float2*)(outl + (size_t)dst * KP1 + cc) = *(float2*)lo4;
    }
}

// ---------------- layer-2 aggregate over emb1, column-sliced (XCD-affine) ----------------
// block (dst, slice): slice = blockIdx&7 handles cols [slice*128, slice*128+128).
// Per-XCD working set: 10000 x 512 B = 5.1 MB (~L2). 8 edge-groups x 32 slots.

__global__ __launch_bounds__(256) void aggregate_d_slice(
        const float* __restrict__ h, const float* __restrict__ hs,
        const float* __restrict__ hd, const float* __restrict__ stats,
        const int* __restrict__ offs, const int* __restrict__ ssrc,
        __hip_bfloat16* __restrict__ outh, __hip_bfloat16* __restrict__ outl) {
    int bid = blockIdx.x;
    int dst = bid >> 3, slice = bid & 7;
    int t = threadIdx.x;
    int g = t >> 5, s = t & 31;           // 8 groups x 32 slots
    int c = slice * 128 + s * 4;
    int start = offs[dst], end = offs[dst + 1];
    float2 st = *(const float2*)(stats + 2 * dst);
    float m = st.x, inv = st.y;
    float hdi = hd[dst];
    __shared__ float part[7][32][4];

    float4 a = {0.f, 0.f, 0.f, 0.f};
    int p = start + g;
    for (; p + 8 < end; p += 16) {
        int j0 = ssrc[p], j1 = ssrc[p + 8];
        float s0 = hs[j0] + hdi; s0 = (s0 >= 0.f) ? s0 : s0 * NEG_SLOPE;
        float s1 = hs[j1] + hdi; s1 = (s1 >= 0.f) ? s1 : s1 * NEG_SLOPE;
        float w0 = __expf(s0 - m), w1 = __expf(s1 - m);
        float4 v0 = *(const float4*)(h + (size_t)j0 * D + c);
        float4 v1 = *(const float4*)(h + (size_t)j1 * D + c);
        a.x += w0 * v0.x + w1 * v1.x;
        a.y += w0 * v0.y + w1 * v1.y;
        a.z += w0 * v0.z + w1 * v1.z;
        a.w += w0 * v0.w + w1 * v1.w;
    }
    if (p < end) {
        int j0 = ssrc[p];
        float s0 = hs[j0] + hdi; s0 = (s0 >= 0.f) ? s0 : s0 * NEG_SLOPE;
        float w0 = __expf(s0 - m);
        float4 v0 = *(const float4*)(h + (size_t)j0 * D + c);
        a.x += w0 * v0.x; a.y += w0 * v0.y; a.z += w0 * v0.z; a.w += w0 * v0.w;
    }
    if (g > 0) {
        part[g - 1][s][0] = a.x; part[g - 1][s][1] = a.y;
        part[g - 1][s][2] = a.z; part[g - 1][s][3] = a.w;
    }
    __syncthreads();
    if (t < 32) {
        #pragma unroll
        for (int q = 0; q < 7; ++q) {
            a.x += part[q][t][0]; a.y += part[q][t][1];
            a.z += part[q][t][2]; a.w += part[q][t][3];
        }
        float rv[4] = {a.x * inv, a.y * inv, a.z * inv, a.w * inv};
        __hip_bfloat16 hi4[4], lo4[4];
        #pragma unroll
        for (int q = 0; q < 4; ++q) {
            __hip_bfloat16 hi = __float2bfloat16(rv[q]);
            hi4[q] = hi;
            lo4[q] = __float2bfloat16(rv[q] - __bfloat162float(hi));
        }
        int cc = slice * 128 + t * 4;
        *(float2*)(outh + (size_t)dst * KP2 + cc) = *(float2*)hi4;
        *(float2*)(outl + (size_t)dst * KP2 + cc) = *(float2*)lo4;
    }
}

// ---------------- split-bf16 MFMA GEMM, combined-stage BK=32 ----------------
// C = relu((Ah+Al)@(BTh+BTl)^T + bias); optional fused dots of the post-relu
// row with asrc/adst -> atomicAdd into hs/hd (next layer's attention scores).

__global__ __launch_bounds__(256) void gemm_split_mfma(
        const __hip_bfloat16* __restrict__ Ah, const __hip_bfloat16* __restrict__ Al,
        const __hip_bfloat16* __restrict__ BTh, const __hip_bfloat16* __restrict__ BTl,
        float* __restrict__ C, const float* __restrict__ bias,
        const float* __restrict__ asrc, const float* __restrict__ adst,
        float* __restrict__ hs, float* __restrict__ hd,
        int Mreal, int Kp, int dots) {
    __shared__ char lds[32768];
    char* Ah_s = lds;
    char* Al_s = lds + 8192;
    char* Bh_s = lds + 16384;
    char* Bl_s = lds + 24576;
    const int t    = threadIdx.x;
    const int lane = t & 63;
    const int wid  = t >> 6;
    const int chunkg = (int)gridDim.x >> 3;
    const int vid  = ((int)blockIdx.x & 7) * chunkg + ((int)blockIdx.x >> 3);
    const int n0 = (vid & 7) * 128;
    const int m0 = (vid >> 3) * 128;
    const int wr = (wid >> 1) * 64;
    const int wc = (wid & 1) * 64;
    const int fr = lane & 15;
    const int kg = lane >> 4;

    const int r0 = t >> 2, s0 = t & 3;
    const int r1 = r0 + 64;
    const int g0 = (s0 ^ ((r0 >> 1) & 3)) << 3;
    const int g1 = (s0 ^ ((r1 >> 1) & 3)) << 3;
    const size_t oA0 = (size_t)(m0 + r0) * Kp + g0;
    const size_t oA1 = (size_t)(m0 + r1) * Kp + g1;
    const size_t oB0 = (size_t)(n0 + r0) * Kp + g0;
    const size_t oB1 = (size_t)(n0 + r1) * Kp + g1;
    const int ko = (kg ^ ((fr >> 1) & 3)) << 4;

    f32x4 acc[4][4] = {};

    for (int kb = 0; kb < Kp; kb += 32) {
        GLOAD_LDS16(Ah  + oA0 + kb, Ah_s + t * 16);
        GLOAD_LDS16(Ah  + oA1 + kb, Ah_s + 4096 + t * 16);
        GLOAD_LDS16(Al  + oA0 + kb, Al_s + t * 16);
        GLOAD_LDS16(Al  + oA1 + kb, Al_s + 4096 + t * 16);
        GLOAD_LDS16(BTh + oB0 + kb, Bh_s + t * 16);
        GLOAD_LDS16(BTh + oB1 + kb, Bh_s + 4096 + t * 16);
        GLOAD_LDS16(BTl + oB0 + kb, Bl_s + t * 16);
        GLOAD_LDS16(BTl + oB1 + kb, Bl_s + 4096 + t * 16);
        __syncthreads();

        bf16x8 ah[4], al[4], bh[4], bl[4];
        #pragma unroll
        for (int f = 0; f < 4; ++f) {
            int ra = (wr + f * 16 + fr) * 64 + ko;
            int rb = (wc + f * 16 + fr) * 64 + ko;
            ah[f] = *(const bf16x8*)(Ah_s + ra);
            al[f] = *(const bf16x8*)(Al_s + ra);
            bh[f] = *(const bf16x8*)(Bh_s + rb);
            bl[f] = *(const bf16x8*)(Bl_s + rb);
        }
        #pragma unroll
        for (int fm = 0; fm < 4; ++fm)
            #pragma unroll
            for (int fn = 0; fn < 4; ++fn)
                acc[fm][fn] = __builtin_amdgcn_mfma_f32_16x16x32_bf16(
                    ah[fm], bh[fn], acc[fm][fn], 0, 0, 0);
        #pragma unroll
        for (int fm = 0; fm < 4; ++fm)
            #pragma unroll
            for (int fn = 0; fn < 4; ++fn)
                acc[fm][fn] = __builtin_amdgcn_mfma_f32_16x16x32_bf16(
                    al[fm], bh[fn], acc[fm][fn], 0, 0, 0);
        #pragma unroll
        for (int fm = 0; fm < 4; ++fm)
            #pragma unroll
            for (int fn = 0; fn < 4; ++fn)
                acc[fm][fn] = __builtin_amdgcn_mfma_f32_16x16x32_bf16(
                    ah[fm], bl[fn], acc[fm][fn], 0, 0, 0);
        __syncthreads();
    }

    // epilogue: bias + relu, write C; C/D layout col=lane&15, row=(lane>>4)*4+j
    float bv[4];
    #pragma unroll
    for (int fn = 0; fn < 4; ++fn) bv[fn] = bias[n0 + wc + fn * 16 + fr];
    #pragma unroll
    for (int fm = 0; fm < 4; ++fm) {
        int mb = m0 + wr + fm * 16 + kg * 4;
        #pragma unroll
        for (int fn = 0; fn < 4; ++fn) {
            int cn = n0 + wc + fn * 16 + fr;
            #pragma unroll
            for (int j = 0; j < 4; ++j) {
                float r = fmaxf(acc[fm][fn][j] + bv[fn], 0.f);
                acc[fm][fn][j] = r;
                int m = mb + j;
                if (m < Mreal) C[(size_t)m * 1024 + cn] = r;
            }
        }
    }

    if (dots) {
        float av[4], dv[4];
        #pragma unroll
        for (int fn = 0; fn < 4; ++fn) {
            int cn = n0 + wc + fn * 16 + fr;
            av[fn] = asrc[cn];
            dv[fn] = adst[cn];
        }
        #pragma unroll
        for (int fm = 0; fm < 4; ++fm) {
            #pragma unroll
            for (int j = 0; j < 4; ++j) {
                float v1 = acc[fm][0][j] * av[0] + acc[fm][1][j] * av[1]
                         + acc[fm][2][j] * av[2] + acc[fm][3][j] * av[3];
                float v2 = acc[fm][0][j] * dv[0] + acc[fm][1][j] * dv[1]
                         + acc[fm][2][j] * dv[2] + acc[fm][3][j] * dv[3];
                #pragma unroll
                for (int o = 1; o < 16; o <<= 1) {
                    v1 += __shfl_xor(v1, o);
                    v2 += __shfl_xor(v2, o);
                }
                int m = m0 + wr + fm * 16 + kg * 4 + j;
                if (fr == 0 && m < Mreal) {
                    atomicAdd(&hs[m], v1);
                    atomicAdd(&hd[m], v2);
                }
            }
        }
    }
}

// ---------------- final fc + softmax ----------------

__global__ void fc_softmax(const float* __restrict__ emb, const float* __restrict__ fcw,
                           const float* __restrict__ fcb, float* __restrict__ out) {
    int wid  = (int)((blockIdx.x * blockDim.x + threadIdx.x) >> 6);
    int lane = threadIdx.x & 63;
    if (wid >= N_NODES) return;
    float acc[N_CLS] = {};
    const float* row = emb + (size_t)wid * D;
    for (int k = lane * 4; k < D; k += 256) {
        float4 v = *(const float4*)(row + k);
        #pragma unroll
        for (int c = 0; c < N_CLS; ++c)
            acc[c] += v.x * fcw[k * N_CLS + c] + v.y * fcw[(k+1) * N_CLS + c]
                    + v.z * fcw[(k+2) * N_CLS + c] + v.w * fcw[(k+3) * N_CLS + c];
    }
    #pragma unroll
    for (int c = 0; c < N_CLS; ++c) {
        #pragma unroll
        for (int o = 32; o; o >>= 1) acc[c] += __shfl_xor(acc[c], o);
    }
    if (lane == 0) {
        float logit[N_CLS];
        float m = -INFINITY;
        #pragma unroll
        for (int c = 0; c < N_CLS; ++c) { logit[c] = acc[c] + fcb[c]; m = fmaxf(m, logit[c]); }
        float s = 0.f;
        #pragma unroll
        for (int c = 0; c < N_CLS; ++c) { logit[c] = __expf(logit[c] - m); s += logit[c]; }
        float invs = 1.0f / s;
        #pragma unroll
        for (int c = 0; c < N_CLS; ++c) out[(size_t)wid * N_CLS + c] = logit[c] * invs;
    }
}

// ---------------- launch ----------------

extern "C" void kernel_launch(void* const* d_in, const int* in_sizes, int n_in,
                              void* d_out, int out_size, void* d_ws, size_t ws_size,
                              hipStream_t stream) {
    const float* x        = (const float*)d_in[0];
    const int*   ei       = (const int*)d_in[1];
    const float* W1       = (const float*)d_in[2];
    const float* att_src1 = (const float*)d_in[3];
    const float* att_dst1 = (const float*)d_in[4];
    const float* b1       = (const float*)d_in[5];
    const float* W2       = (const float*)d_in[6];
    const float* att_src2 = (const float*)d_in[7];
    const float* att_dst2 = (const float*)d_in[8];
    const float* b2       = (const float*)d_in[9];
    const float* fc_w     = (const float*)d_in[10];
    const float* fc_b     = (const float*)d_in[11];
    float* out = (float*)d_out;

    const int* src = ei;
    const int* dst = ei + N_EDGES;

    char* w = (char*)d_ws;
    #define ALLOC(name, bytes) char* name = w; w += (((size_t)(bytes) + 255) & ~(size_t)255)
    ALLOC(p_emb,   (size_t)N_NODES * D * 4);           // emb1, later emb2 (aliased)
    ALLOC(p_hs1,   (size_t)N_NODES * 4);
    ALLOC(p_hd1,   (size_t)N_NODES * 4);
    ALLOC(p_hs2,   (size_t)N_NODES * 4);
    ALLOC(p_hd2,   (size_t)N_NODES * 4);
    ALLOC(p_st1,   (size_t)N_NODES * 8);               // stats layer 1 {m, inv}
    ALLOC(p_st2,   (size_t)N_NODES * 8);               // stats layer 2
    ALLOC(p_deg,   (size_t)N_NODES * 4);
    ALLOC(p_offs,  (size_t)(N_NODES + 1) * 4);
    ALLOC(p_pos,   (size_t)N_NODES * 4);
    ALLOC(p_ssrc,  (size_t)E_TOT * 4);
    ALLOC(p_u1,    (size_t)F_IN * 4);
    ALLOC(p_v1,    (size_t)F_IN * 4);
    ALLOC(p_u2,    (size_t)D * 4);
    ALLOC(p_v2,    (size_t)D * 4);
    ALLOC(p_as1,   (size_t)2 * MP * KP1 * 2);          // Ah1|Al1
    ALLOC(p_as2,   (size_t)2 * MP * KP2 * 2);          // Ah2|Al2
    ALLOC(p_bt1,   (size_t)2 * D * KP1 * 2);           // BT1h|BT1l
    ALLOC(p_bt2,   (size_t)2 * D * KP2 * 2);           // BT2h|BT2l
    #undef ALLOC

    float* emb  = (float*)p_emb;
    float* hs1  = (float*)p_hs1;
    float* hd1  = (float*)p_hd1;
    float* hs2  = (float*)p_hs2;
    float* hd2  = (float*)p_hd2;
    float* st1  = (float*)p_st1;
    float* st2  = (float*)p_st2;
    int*   deg  = (int*)p_deg;
    int*   offs = (int*)p_offs;
    int*   pos  = (int*)p_pos;
    int*   ssrc = (int*)p_ssrc;
    float* u1 = (float*)p_u1; float* v1 = (float*)p_v1;
    float* u2 = (float*)p_u2; float* v2 = (float*)p_v2;
    __hip_bfloat16* Ah1  = (__hip_bfloat16*)p_as1;
    __hip_bfloat16* Al1  = Ah1 + (size_t)MP * KP1;
    __hip_bfloat16* Ah2  = (__hip_bfloat16*)p_as2;
    __hip_bfloat16* Al2  = Ah2 + (size_t)MP * KP2;
    __hip_bfloat16* BT1h = (__hip_bfloat16*)p_bt1;
    __hip_bfloat16* BT1l = BT1h + (size_t)D * KP1;
    __hip_bfloat16* BT2h = (__hip_bfloat16*)p_bt2;
    __hip_bfloat16* BT2l = BT2h + (size_t)D * KP2;

    // CSR build
    init_deg<<<(N_NODES + 255) / 256, 256, 0, stream>>>(deg);
    count_edges<<<(N_EDGES + 255) / 256, 256, 0, stream>>>(dst, deg);
    scan_offs<<<1, 1024, 0, stream>>>(deg, offs, pos);
    scatter_edges<<<(E_TOT + 255) / 256, 256, 0, stream>>>(src, dst, pos, ssrc);

    // projected attention vectors + weight transposes + zero pads
    prep_uv<<<((F_IN + D) * 64 + 255) / 256, 256, 0, stream>>>(
        W1, att_src1, att_dst1, W2, att_src2, att_dst2, u1, v1, u2, v2);
    dim3 tb(32, 8);
    transpose_split<<<dim3(KP1 / 32, D / 32), tb, 0, stream>>>(W1, BT1h, BT1l, F_IN, D, KP1);
    transpose_split<<<dim3(KP2 / 32, D / 32), tb, 0, stream>>>(W2, BT2h, BT2l, D, D, KP2);
    zero_misc<<<(ZTOT + 255) / 256, 256, 0, stream>>>(hs2, hd2, Ah1, Al1, Ah2, Al2);

    const int gemmGrid = (D / 128) * (MP / 128);   // 632 = 8*79
    const int aggGrid  = N_NODES * 8;              // (dst, slice) pairs

    // layer 1: scores from x.(W1 a), stats, sliced aggregate of x, then GEMM
    node_scores_x<<<(N_NODES * 64 + 255) / 256, 256, 0, stream>>>(x, u1, v1, hs1, hd1);
    seg_stats<<<(N_NODES * 64 + 255) / 256, 256, 0, stream>>>(hs1, hd1, offs, ssrc, st1);
    aggregate_x_slice<<<aggGrid, 256, 0, stream>>>(x, hs1, hd1, st1, offs, ssrc, Ah1, Al1);
    gemm_split_mfma<<<gemmGrid, 256, 0, stream>>>(Ah1, Al1, BT1h, BT1l, emb, b1,
                                                  u2, v2, hs2, hd2, N_NODES, KP1, 1);

    // layer 2: stats, sliced aggregate of emb1, then GEMM (+b2, relu) -> emb2
    seg_stats<<<(N_NODES * 64 + 255) / 256, 256, 0, stream>>>(hs2, hd2, offs, ssrc, st2);
    aggregate_d_slice<<<aggGrid, 256, 0, stream>>>(emb, hs2, hd2, st2, offs, ssrc, Ah2, Al2);
    gemm_split_mfma<<<gemmGrid, 256, 0, stream>>>(Ah2, Al2, BT2h, BT2l, emb, b2,
                                                  (const float*)nullptr, (const float*)nullptr,
                                                  (float*)nullptr, (float*)nullptr,
                                                  N_NODES, KP2, 0);

    // classifier
    fc_softmax<<<(N_NODES * 64 + 255) / 256, 256, 0, stream>>>(emb, fc_w, fc_b, out);
}

// Round 10
// 381.464 us; speedup vs baseline: 1.1835x; 1.1835x over previous
//
#include <hip/hip_runtime.h>
#include <hip/hip_bf16.h>
#include <hip/hip_fp16.h>
#include <math.h>

#define N_NODES 10000
#define N_EDGES 160000
#define E_TOT   (N_EDGES + N_NODES)
#define F_IN    300
#define D       1024
#define N_CLS   10
#define NEG_SLOPE 0.2f

#define MP      10112              // 79 * 128, padded M
#define KP1     320                // F_IN padded to mult of 32
#define KP2     1024

typedef __attribute__((ext_vector_type(8))) _Float16 f16x8;
typedef __attribute__((ext_vector_type(4))) float f32x4;

#define GLOAD_LDS16(g, l) __builtin_amdgcn_global_load_lds( \
    (const __attribute__((address_space(1))) void*)(g), \
    (__attribute__((address_space(3))) void*)(l), 16, 0, 0)

// ---------------- CSR build ----------------

__global__ void init_deg(int* __restrict__ deg) {
    int i = blockIdx.x * blockDim.x + threadIdx.x;
    if (i < N_NODES) deg[i] = 1;  // self loop
}

__global__ void count_edges(const int* __restrict__ dst, int* __restrict__ deg) {
    int e = blockIdx.x * blockDim.x + threadIdx.x;
    if (e < N_EDGES) atomicAdd(&deg[dst[e]], 1);
}

__global__ void scan_offs(const int* __restrict__ deg, int* __restrict__ offs,
                          int* __restrict__ pos) {
    __shared__ int sbuf[1024];
    __shared__ int scarry;
    int t = threadIdx.x;
    if (t == 0) { scarry = 0; offs[0] = 0; }
    __syncthreads();
    for (int base = 0; base < N_NODES; base += 1024) {
        int v = (base + t < N_NODES) ? deg[base + t] : 0;
        sbuf[t] = v;
        __syncthreads();
        for (int off = 1; off < 1024; off <<= 1) {
            int add = (t >= off) ? sbuf[t - off] : 0;
            __syncthreads();
            sbuf[t] += add;
            __syncthreads();
        }
        int carry = scarry;
        if (base + t < N_NODES) {
            int incl = carry + sbuf[t];
            offs[base + t + 1] = incl;
            pos[base + t]      = incl - v;
        }
        __syncthreads();
        if (t == 1023) scarry = carry + sbuf[1023];
        __syncthreads();
    }
}

__global__ void scatter_edges(const int* __restrict__ src, const int* __restrict__ dst,
                              int* __restrict__ pos, int* __restrict__ ssrc) {
    int e = blockIdx.x * blockDim.x + threadIdx.x;
    if (e < N_EDGES) {
        int d = dst[e];
        int p = atomicAdd(&pos[d], 1);
        ssrc[p] = src[e];
    } else if (e < E_TOT) {
        int i = e - N_EDGES;
        int p = atomicAdd(&pos[i], 1);
        ssrc[p] = i;
    }
}

// ---------------- projected attention vectors: u = W @ a_src, v = W @ a_dst ----------------

__global__ void prep_uv(const float* __restrict__ W1, const float* __restrict__ as1,
                        const float* __restrict__ ad1, const float* __restrict__ W2,
                        const float* __restrict__ as2, const float* __restrict__ ad2,
                        float* __restrict__ u1, float* __restrict__ v1,
                        float* __restrict__ u2, float* __restrict__ v2) {
    int wid  = (int)((blockIdx.x * blockDim.x + threadIdx.x) >> 6);
    int lane = threadIdx.x & 63;
    const float* row;
    const float* a;
    const float* b;
    float *du, *dv;
    int k;
    if (wid < F_IN) {
        k = wid; row = W1 + (size_t)k * D; a = as1; b = ad1; du = u1; dv = v1;
    } else if (wid < F_IN + D) {
        k = wid - F_IN; row = W2 + (size_t)k * D; a = as2; b = ad2; du = u2; dv = v2;
    } else return;
    float s1 = 0.f, s2 = 0.f;
    for (int n = lane; n < D; n += 64) {
        float w = row[n];
        s1 += w * a[n];
        s2 += w * b[n];
    }
    #pragma unroll
    for (int o = 32; o; o >>= 1) { s1 += __shfl_xor(s1, o); s2 += __shfl_xor(s2, o); }
    if (lane == 0) { du[k] = s1; dv[k] = s2; }
}

// ---------------- layer-1 node scores: hs1[i] = x_i . u1, hd1[i] = x_i . v1 ----------------

__global__ void node_scores_x(const float* __restrict__ x, const float* __restrict__ u1,
                              const float* __restrict__ v1, float* __restrict__ hs,
                              float* __restrict__ hd) {
    int wid  = (int)((blockIdx.x * blockDim.x + threadIdx.x) >> 6);
    int lane = threadIdx.x & 63;
    if (wid >= N_NODES) return;
    const float* row = x + (size_t)wid * F_IN;
    float s1 = 0.f, s2 = 0.f;
    for (int k = lane; k < F_IN; k += 64) {
        float v = row[k];
        s1 += v * u1[k];
        s2 += v * v1[k];
    }
    #pragma unroll
    for (int o = 32; o; o >>= 1) { s1 += __shfl_xor(s1, o); s2 += __shfl_xor(s2, o); }
    if (lane == 0) { hs[wid] = s1; hd[wid] = s2; }
}

// ---------------- zero hs2/hd2 + pad regions of the A-split buffers ----------------

#define ZR1 (112 * KP1)        // asplit1 pad rows, per plane
#define ZR2 (N_NODES * 20)     // asplit1 pad cols (300..319), per plane
#define ZR3 (112 * KP2)        // asplit2 pad rows, per plane
#define ZTOT (2*ZR1 + 2*ZR2 + 2*ZR3 + 2*N_NODES)

__global__ void zero_misc(float* __restrict__ hs2, float* __restrict__ hd2,
                          unsigned short* __restrict__ Ah1, unsigned short* __restrict__ Al1,
                          unsigned short* __restrict__ Ah2, unsigned short* __restrict__ Al2) {
    int idx = blockIdx.x * blockDim.x + threadIdx.x;
    if (idx >= ZTOT) return;
    if (idx < 2 * ZR1) {
        unsigned short* B = (idx < ZR1) ? Ah1 : Al1;
        int off = (idx < ZR1) ? idx : idx - ZR1;
        B[(size_t)N_NODES * KP1 + off] = 0;
    } else if ((idx -= 2 * ZR1) < 2 * ZR2) {
        unsigned short* B = (idx < ZR2) ? Ah1 : Al1;
        int off = (idx < ZR2) ? idx : idx - ZR2;
        int r = off / 20, c = 300 + off % 20;
        B[(size_t)r * KP1 + c] = 0;
    } else if ((idx -= 2 * ZR2) < 2 * ZR3) {
        unsigned short* B = (idx < ZR3) ? Ah2 : Al2;
        int off = (idx < ZR3) ? idx : idx - ZR3;
        B[(size_t)N_NODES * KP2 + off] = 0;
    } else {
        idx -= 2 * ZR3;
        if (idx < N_NODES) hs2[idx] = 0.f;
        else hd2[idx - N_NODES] = 0.f;
    }
}

// ---------------- transpose W [K][N] -> BT [N][Kp] (single fp16 plane) ----------------

__global__ void transpose_f16(const float* __restrict__ W, _Float16* __restrict__ BTh,
                              int K, int N, int Kp) {
    __shared__ float tile[32][33];
    int k0 = blockIdx.x * 32, n0 = blockIdx.y * 32;
    int tx = threadIdx.x, ty = threadIdx.y;
    #pragma unroll
    for (int j = 0; j < 32; j += 8) {
        int k = k0 + ty + j;
        tile[ty + j][tx] = (k < K) ? W[(size_t)k * N + n0 + tx] : 0.f;
    }
    __syncthreads();
    #pragma unroll
    for (int j = 0; j < 32; j += 8) {
        int n = n0 + ty + j;
        int k = k0 + tx;
        BTh[(size_t)n * Kp + k] = (_Float16)tile[tx][ty + j];
    }
}

// ---------------- layer-1 aggregate over raw x (300-wide) ----------------
// agg[i] = (1/denom) * sum_j exp(e_ij - m) * x_j ; output hi/lo fp16 planes
// [MP][KP1]. 3 edge-groups x 75 lanes (75 float4 slots per row), 2-deep unroll.

__global__ __launch_bounds__(256) void aggregate_x(
        const float* __restrict__ x, const float* __restrict__ hs,
        const float* __restrict__ hd, const int* __restrict__ offs,
        const int* __restrict__ ssrc, _Float16* __restrict__ outh,
        _Float16* __restrict__ outl) {
    int i = blockIdx.x;
    int t = threadIdx.x;
    int lane = t & 63;
    int wv = t >> 6;
    int start = offs[i], end = offs[i + 1];
    __shared__ float red[8];
    __shared__ float part[2][75][4];
    float hdi = hd[i];

    // block max
    float lmax = -INFINITY;
    for (int p = start + t; p < end; p += 256) {
        float s = hs[ssrc[p]] + hdi;
        s = (s >= 0.f) ? s : s * NEG_SLOPE;
        lmax = fmaxf(lmax, s);
    }
    #pragma unroll
    for (int o = 32; o; o >>= 1) lmax = fmaxf(lmax, __shfl_xor(lmax, o));
    if (lane == 0) red[wv] = lmax;
    __syncthreads();
    float m = fmaxf(fmaxf(red[0], red[1]), fmaxf(red[2], red[3]));

    // block sum of exp
    float lsum = 0.f;
    for (int p = start + t; p < end; p += 256) {
        float s = hs[ssrc[p]] + hdi;
        s = (s >= 0.f) ? s : s * NEG_SLOPE;
        lsum += __expf(s - m);
    }
    #pragma unroll
    for (int o = 32; o; o >>= 1) lsum += __shfl_xor(lsum, o);
    if (lane == 0) red[4 + wv] = lsum;
    __syncthreads();
    float inv = 1.0f / (red[4] + red[5] + red[6] + red[7]);

    // weighted gather over x rows, 3 groups x 75 slots
    int g = t / 75;
    int s = t - g * 75;
    int c = s * 4;
    float4 a = {0.f, 0.f, 0.f, 0.f};
    if (t < 225) {
        int p = start + g;
        for (; p + 3 < end; p += 6) {
            int j0 = ssrc[p], j1 = ssrc[p + 3];
            float s0 = hs[j0] + hdi; s0 = (s0 >= 0.f) ? s0 : s0 * NEG_SLOPE;
            float s1 = hs[j1] + hdi; s1 = (s1 >= 0.f) ? s1 : s1 * NEG_SLOPE;
            float w0 = __expf(s0 - m), w1 = __expf(s1 - m);
            float4 v0 = *(const float4*)(x + (size_t)j0 * F_IN + c);
            float4 v1 = *(const float4*)(x + (size_t)j1 * F_IN + c);
            a.x += w0 * v0.x + w1 * v1.x;
            a.y += w0 * v0.y + w1 * v1.y;
            a.z += w0 * v0.z + w1 * v1.z;
            a.w += w0 * v0.w + w1 * v1.w;
        }
        if (p < end) {
            int j0 = ssrc[p];
            float s0 = hs[j0] + hdi; s0 = (s0 >= 0.f) ? s0 : s0 * NEG_SLOPE;
            float w0 = __expf(s0 - m);
            float4 v0 = *(const float4*)(x + (size_t)j0 * F_IN + c);
            a.x += w0 * v0.x; a.y += w0 * v0.y; a.z += w0 * v0.z; a.w += w0 * v0.w;
        }
    }
    if (t < 225 && g > 0) {
        part[g - 1][s][0] = a.x; part[g - 1][s][1] = a.y;
        part[g - 1][s][2] = a.z; part[g - 1][s][3] = a.w;
    }
    __syncthreads();
    if (t < 75) {
        a.x += part[0][t][0] + part[1][t][0];
        a.y += part[0][t][1] + part[1][t][1];
        a.z += part[0][t][2] + part[1][t][2];
        a.w += part[0][t][3] + part[1][t][3];
        float rv[4] = {a.x * inv, a.y * inv, a.z * inv, a.w * inv};
        _Float16 hi4[4], lo4[4];
        #pragma unroll
        for (int q = 0; q < 4; ++q) {
            _Float16 hi = (_Float16)rv[q];
            hi4[q] = hi;
            lo4[q] = (_Float16)(rv[q] - (float)hi);
        }
        *(float2*)(outh + (size_t)i * KP1 + c) = *(float2*)hi4;
        *(float2*)(outl + (size_t)i * KP1 + c) = *(float2*)lo4;
    }
}

// ---------------- layer-2 aggregate over emb1 (1024-wide) ----------------
// output hi/lo fp16 planes [MP][KP2]; bias/relu moved to GEMM-2 epilogue

__global__ __launch_bounds__(256) void aggregate_d(
        const float* __restrict__ h, const float* __restrict__ hs,
        const float* __restrict__ hd, const int* __restrict__ offs,
        const int* __restrict__ ssrc, _Float16* __restrict__ outh,
        _Float16* __restrict__ outl) {
    int i = blockIdx.x;
    int t = threadIdx.x;
    int lane = t & 63;
    int wv = t >> 6;
    int start = offs[i], end = offs[i + 1];
    __shared__ float red[8];
    float hdi = hd[i];

    float lmax = -INFINITY;
    for (int p = start + t; p < end; p += 256) {
        float s = hs[ssrc[p]] + hdi;
        s = (s >= 0.f) ? s : s * NEG_SLOPE;
        lmax = fmaxf(lmax, s);
    }
    #pragma unroll
    for (int o = 32; o; o >>= 1) lmax = fmaxf(lmax, __shfl_xor(lmax, o));
    if (lane == 0) red[wv] = lmax;
    __syncthreads();
    float m = fmaxf(fmaxf(red[0], red[1]), fmaxf(red[2], red[3]));

    float lsum = 0.f;
    for (int p = start + t; p < end; p += 256) {
        float s = hs[ssrc[p]] + hdi;
        s = (s >= 0.f) ? s : s * NEG_SLOPE;
        lsum += __expf(s - m);
    }
    #pragma unroll
    for (int o = 32; o; o >>= 1) lsum += __shfl_xor(lsum, o);
    if (lane == 0) red[4 + wv] = lsum;
    __syncthreads();
    float inv = 1.0f / (red[4] + red[5] + red[6] + red[7]);

    int c = t * 4;
    float4 a0 = {0.f,0.f,0.f,0.f}, a1 = a0, a2 = a0, a3 = a0;
    int p = start;
    for (; p + 4 <= end; p += 4) {
        int j0 = ssrc[p], j1 = ssrc[p+1], j2 = ssrc[p+2], j3 = ssrc[p+3];
        float s0 = hs[j0] + hdi; s0 = (s0 >= 0.f) ? s0 : s0 * NEG_SLOPE;
        float s1 = hs[j1] + hdi; s1 = (s1 >= 0.f) ? s1 : s1 * NEG_SLOPE;
        float s2 = hs[j2] + hdi; s2 = (s2 >= 0.f) ? s2 : s2 * NEG_SLOPE;
        float s3 = hs[j3] + hdi; s3 = (s3 >= 0.f) ? s3 : s3 * NEG_SLOPE;
        float w0 = __expf(s0 - m), w1 = __expf(s1 - m);
        float w2 = __expf(s2 - m), w3 = __expf(s3 - m);
        float4 v0 = *(const float4*)(h + (size_t)j0 * D + c);
        float4 v1 = *(const float4*)(h + (size_t)j1 * D + c);
        float4 v2 = *(const float4*)(h + (size_t)j2 * D + c);
        float4 v3 = *(const float4*)(h + (size_t)j3 * D + c);
        a0.x += w0*v0.x; a0.y += w0*v0.y; a0.z += w0*v0.z; a0.w += w0*v0.w;
        a1.x += w1*v1.x; a1.y += w1*v1.y; a1.z += w1*v1.z; a1.w += w1*v1.w;
        a2.x += w2*v2.x; a2.y += w2*v2.y; a2.z += w2*v2.z; a2.w += w2*v2.w;
        a3.x += w3*v3.x; a3.y += w3*v3.y; a3.z += w3*v3.z; a3.w += w3*v3.w;
    }
    for (; p < end; ++p) {
        int j0 = ssrc[p];
        float s0 = hs[j0] + hdi; s0 = (s0 >= 0.f) ? s0 : s0 * NEG_SLOPE;
        float w0 = __expf(s0 - m);
        float4 v0 = *(const float4*)(h + (size_t)j0 * D + c);
        a0.x += w0*v0.x; a0.y += w0*v0.y; a0.z += w0*v0.z; a0.w += w0*v0.w;
    }
    float rv[4];
    rv[0] = ((a0.x + a1.x) + (a2.x + a3.x)) * inv;
    rv[1] = ((a0.y + a1.y) + (a2.y + a3.y)) * inv;
    rv[2] = ((a0.z + a1.z) + (a2.z + a3.z)) * inv;
    rv[3] = ((a0.w + a1.w) + (a2.w + a3.w)) * inv;
    _Float16 hi4[4], lo4[4];
    #pragma unroll
    for (int q = 0; q < 4; ++q) {
        _Float16 hi = (_Float16)rv[q];
        hi4[q] = hi;
        lo4[q] = (_Float16)(rv[q] - (float)hi);
    }
    *(float2*)(outh + (size_t)i * KP2 + c) = *(float2*)hi4;
    *(float2*)(outl + (size_t)i * KP2 + c) = *(float2*)lo4;
}

// ---------------- split-fp16 MFMA GEMM, combined-stage BK=32, 2-term ----------------
// C = relu((Ah+Al)@Bh^T + bias), A exact to ~2^-22 (fp16 hi/lo), B rounded to
// fp16 (dropped A@Bl term ~2^-11 rel, sign-cancelled over K). 3 staged tiles,
// 32 MFMA/K-step. Optional fused dots of post-relu rows -> hs/hd atomicAdd.

__global__ __launch_bounds__(256) void gemm_split_mfma(
        const _Float16* __restrict__ Ah, const _Float16* __restrict__ Al,
        const _Float16* __restrict__ BTh,
        float* __restrict__ C, const float* __restrict__ bias,
        const float* __restrict__ asrc, const float* __restrict__ adst,
        float* __restrict__ hs, float* __restrict__ hd,
        int Mreal, int Kp, int dots) {
    __shared__ char lds[24576];
    char* Ah_s = lds;
    char* Al_s = lds + 8192;
    char* Bh_s = lds + 16384;
    const int t    = threadIdx.x;
    const int lane = t & 63;
    const int wid  = t >> 6;
    const int chunkg = (int)gridDim.x >> 3;
    const int vid  = ((int)blockIdx.x & 7) * chunkg + ((int)blockIdx.x >> 3);
    const int n0 = (vid & 7) * 128;
    const int m0 = (vid >> 3) * 128;
    const int wr = (wid >> 1) * 64;
    const int wc = (wid & 1) * 64;
    const int fr = lane & 15;
    const int kg = lane >> 4;

    const int r0 = t >> 2, s0 = t & 3;
    const int r1 = r0 + 64;
    const int g0 = (s0 ^ ((r0 >> 1) & 3)) << 3;
    const int g1 = (s0 ^ ((r1 >> 1) & 3)) << 3;
    const size_t oA0 = (size_t)(m0 + r0) * Kp + g0;
    const size_t oA1 = (size_t)(m0 + r1) * Kp + g1;
    const size_t oB0 = (size_t)(n0 + r0) * Kp + g0;
    const size_t oB1 = (size_t)(n0 + r1) * Kp + g1;
    const int ko = (kg ^ ((fr >> 1) & 3)) << 4;

    f32x4 acc[4][4] = {};

    for (int kb = 0; kb < Kp; kb += 32) {
        GLOAD_LDS16(Ah  + oA0 + kb, Ah_s + t * 16);
        GLOAD_LDS16(Ah  + oA1 + kb, Ah_s + 4096 + t * 16);
        GLOAD_LDS16(Al  + oA0 + kb, Al_s + t * 16);
        GLOAD_LDS16(Al  + oA1 + kb, Al_s + 4096 + t * 16);
        GLOAD_LDS16(BTh + oB0 + kb, Bh_s + t * 16);
        GLOAD_LDS16(BTh + oB1 + kb, Bh_s + 4096 + t * 16);
        __syncthreads();

        f16x8 ah[4], al[4], bh[4];
        #pragma unroll
        for (int f = 0; f < 4; ++f) {
            int ra = (wr + f * 16 + fr) * 64 + ko;
            int rb = (wc + f * 16 + fr) * 64 + ko;
            ah[f] = *(const f16x8*)(Ah_s + ra);
            al[f] = *(const f16x8*)(Al_s + ra);
            bh[f] = *(const f16x8*)(Bh_s + rb);
        }
        #pragma unroll
        for (int fm = 0; fm < 4; ++fm)
            #pragma unroll
            for (int fn = 0; fn < 4; ++fn)
                acc[fm][fn] = __builtin_amdgcn_mfma_f32_16x16x32_f16(
                    ah[fm], bh[fn], acc[fm][fn], 0, 0, 0);
        #pragma unroll
        for (int fm = 0; fm < 4; ++fm)
            #pragma unroll
            for (int fn = 0; fn < 4; ++fn)
                acc[fm][fn] = __builtin_amdgcn_mfma_f32_16x16x32_f16(
                    al[fm], bh[fn], acc[fm][fn], 0, 0, 0);
        __syncthreads();
    }

    // epilogue: bias + relu, write C; C/D layout col=lane&15, row=(lane>>4)*4+j
    float bv[4];
    #pragma unroll
    for (int fn = 0; fn < 4; ++fn) bv[fn] = bias[n0 + wc + fn * 16 + fr];
    #pragma unroll
    for (int fm = 0; fm < 4; ++fm) {
        int mb = m0 + wr + fm * 16 + kg * 4;
        #pragma unroll
        for (int fn = 0; fn < 4; ++fn) {
            int cn = n0 + wc + fn * 16 + fr;
            #pragma unroll
            for (int j = 0; j < 4; ++j) {
                float r = fmaxf(acc[fm][fn][j] + bv[fn], 0.f);
                acc[fm][fn][j] = r;
                int m = mb + j;
                if (m < Mreal) C[(size_t)m * 1024 + cn] = r;
            }
        }
    }

    if (dots) {
        float av[4], dv[4];
        #pragma unroll
        for (int fn = 0; fn < 4; ++fn) {
            int cn = n0 + wc + fn * 16 + fr;
            av[fn] = asrc[cn];
            dv[fn] = adst[cn];
        }
        #pragma unroll
        for (int fm = 0; fm < 4; ++fm) {
            #pragma unroll
            for (int j = 0; j < 4; ++j) {
                float v1 = acc[fm][0][j] * av[0] + acc[fm][1][j] * av[1]
                         + acc[fm][2][j] * av[2] + acc[fm][3][j] * av[3];
                float v2 = acc[fm][0][j] * dv[0] + acc[fm][1][j] * dv[1]
                         + acc[fm][2][j] * dv[2] + acc[fm][3][j] * dv[3];
                #pragma unroll
                for (int o = 1; o < 16; o <<= 1) {
                    v1 += __shfl_xor(v1, o);
                    v2 += __shfl_xor(v2, o);
                }
                int m = m0 + wr + fm * 16 + kg * 4 + j;
                if (fr == 0 && m < Mreal) {
                    atomicAdd(&hs[m], v1);
                    atomicAdd(&hd[m], v2);
                }
            }
        }
    }
}

// ---------------- final fc + softmax ----------------

__global__ void fc_softmax(const float* __restrict__ emb, const float* __restrict__ fcw,
                           const float* __restrict__ fcb, float* __restrict__ out) {
    int wid  = (int)((blockIdx.x * blockDim.x + threadIdx.x) >> 6);
    int lane = threadIdx.x & 63;
    if (wid >= N_NODES) return;
    float acc[N_CLS] = {};
    const float* row = emb + (size_t)wid * D;
    for (int k = lane * 4; k < D; k += 256) {
        float4 v = *(const float4*)(row + k);
        #pragma unroll
        for (int c = 0; c < N_CLS; ++c)
            acc[c] += v.x * fcw[k * N_CLS + c] + v.y * fcw[(k+1) * N_CLS + c]
                    + v.z * fcw[(k+2) * N_CLS + c] + v.w * fcw[(k+3) * N_CLS + c];
    }
    #pragma unroll
    for (int c = 0; c < N_CLS; ++c) {
        #pragma unroll
        for (int o = 32; o; o >>= 1) acc[c] += __shfl_xor(acc[c], o);
    }
    if (lane == 0) {
        float logit[N_CLS];
        float m = -INFINITY;
        #pragma unroll
        for (int c = 0; c < N_CLS; ++c) { logit[c] = acc[c] + fcb[c]; m = fmaxf(m, logit[c]); }
        float s = 0.f;
        #pragma unroll
        for (int c = 0; c < N_CLS; ++c) { logit[c] = __expf(logit[c] - m); s += logit[c]; }
        float invs = 1.0f / s;
        #pragma unroll
        for (int c = 0; c < N_CLS; ++c) out[(size_t)wid * N_CLS + c] = logit[c] * invs;
    }
}

// ---------------- launch ----------------

extern "C" void kernel_launch(void* const* d_in, const int* in_sizes, int n_in,
                              void* d_out, int out_size, void* d_ws, size_t ws_size,
                              hipStream_t stream) {
    const float* x        = (const float*)d_in[0];
    const int*   ei       = (const int*)d_in[1];
    const float* W1       = (const float*)d_in[2];
    const float* att_src1 = (const float*)d_in[3];
    const float* att_dst1 = (const float*)d_in[4];
    const float* b1       = (const float*)d_in[5];
    const float* W2       = (const float*)d_in[6];
    const float* att_src2 = (const float*)d_in[7];
    const float* att_dst2 = (const float*)d_in[8];
    const float* b2       = (const float*)d_in[9];
    const float* fc_w     = (const float*)d_in[10];
    const float* fc_b     = (const float*)d_in[11];
    float* out = (float*)d_out;

    const int* src = ei;
    const int* dst = ei + N_EDGES;

    char* w = (char*)d_ws;
    #define ALLOC(name, bytes) char* name = w; w += (((size_t)(bytes) + 255) & ~(size_t)255)
    ALLOC(p_emb,   (size_t)N_NODES * D * 4);           // emb1, later emb2 (aliased)
    ALLOC(p_hs1,   (size_t)N_NODES * 4);
    ALLOC(p_hd1,   (size_t)N_NODES * 4);
    ALLOC(p_hs2,   (size_t)N_NODES * 4);
    ALLOC(p_hd2,   (size_t)N_NODES * 4);
    ALLOC(p_deg,   (size_t)N_NODES * 4);
    ALLOC(p_offs,  (size_t)(N_NODES + 1) * 4);
    ALLOC(p_pos,   (size_t)N_NODES * 4);
    ALLOC(p_ssrc,  (size_t)E_TOT * 4);
    ALLOC(p_u1,    (size_t)F_IN * 4);
    ALLOC(p_v1,    (size_t)F_IN * 4);
    ALLOC(p_u2,    (size_t)D * 4);
    ALLOC(p_v2,    (size_t)D * 4);
    ALLOC(p_as1,   (size_t)2 * MP * KP1 * 2);          // Ah1|Al1 fp16 planes
    ALLOC(p_as2,   (size_t)2 * MP * KP2 * 2);          // Ah2|Al2 fp16 planes
    ALLOC(p_bt1,   (size_t)D * KP1 * 2);               // BT1h fp16
    ALLOC(p_bt2,   (size_t)D * KP2 * 2);               // BT2h fp16
    #undef ALLOC

    float* emb  = (float*)p_emb;
    float* hs1  = (float*)p_hs1;
    float* hd1  = (float*)p_hd1;
    float* hs2  = (float*)p_hs2;
    float* hd2  = (float*)p_hd2;
    int*   deg  = (int*)p_deg;
    int*   offs = (int*)p_offs;
    int*   pos  = (int*)p_pos;
    int*   ssrc = (int*)p_ssrc;
    float* u1 = (float*)p_u1; float* v1 = (float*)p_v1;
    float* u2 = (float*)p_u2; float* v2 = (float*)p_v2;
    _Float16* Ah1  = (_Float16*)p_as1;
    _Float16* Al1  = Ah1 + (size_t)MP * KP1;
    _Float16* Ah2  = (_Float16*)p_as2;
    _Float16* Al2  = Ah2 + (size_t)MP * KP2;
    _Float16* BT1h = (_Float16*)p_bt1;
    _Float16* BT2h = (_Float16*)p_bt2;

    // CSR build
    init_deg<<<(N_NODES + 255) / 256, 256, 0, stream>>>(deg);
    count_edges<<<(N_EDGES + 255) / 256, 256, 0, stream>>>(dst, deg);
    scan_offs<<<1, 1024, 0, stream>>>(deg, offs, pos);
    scatter_edges<<<(E_TOT + 255) / 256, 256, 0, stream>>>(src, dst, pos, ssrc);

    // projected attention vectors + weight transposes + zero pads
    prep_uv<<<((F_IN + D) * 64 + 255) / 256, 256, 0, stream>>>(
        W1, att_src1, att_dst1, W2, att_src2, att_dst2, u1, v1, u2, v2);
    dim3 tb(32, 8);
    transpose_f16<<<dim3(KP1 / 32, D / 32), tb, 0, stream>>>(W1, BT1h, F_IN, D, KP1);
    transpose_f16<<<dim3(KP2 / 32, D / 32), tb, 0, stream>>>(W2, BT2h, D, D, KP2);
    zero_misc<<<(ZTOT + 255) / 256, 256, 0, stream>>>(hs2, hd2,
        (unsigned short*)Ah1, (unsigned short*)Al1,
        (unsigned short*)Ah2, (unsigned short*)Al2);

    const int gemmGrid = (D / 128) * (MP / 128);   // 632 = 8*79

    // layer 1: scores from x.(W1 a), aggregate x, then GEMM (+b1, relu, dots for layer 2)
    node_scores_x<<<(N_NODES * 64 + 255) / 256, 256, 0, stream>>>(x, u1, v1, hs1, hd1);
    aggregate_x<<<N_NODES, 256, 0, stream>>>(x, hs1, hd1, offs, ssrc, Ah1, Al1);
    gemm_split_mfma<<<gemmGrid, 256, 0, stream>>>(Ah1, Al1, BT1h, emb, b1,
                                                  u2, v2, hs2, hd2, N_NODES, KP1, 1);

    // layer 2: aggregate emb1, then GEMM (+b2, relu) -> emb2 (same buffer)
    aggregate_d<<<N_NODES, 256, 0, stream>>>(emb, hs2, hd2, offs, ssrc, Ah2, Al2);
    gemm_split_mfma<<<gemmGrid, 256, 0, stream>>>(Ah2, Al2, BT2h, emb, b2,
                                                  (const float*)nullptr, (const float*)nullptr,
                                                  (float*)nullptr, (float*)nullptr,
                                                  N_NODES, KP2, 0);

    // classifier
    fc_softmax<<<(N_NODES * 64 + 255) / 256, 256, 0, stream>>>(emb, fc_w, fc_b, out);
}

// Round 11
// 338.431 us; speedup vs baseline: 1.3340x; 1.1272x over previous
//
#include <hip/hip_runtime.h>
#include <hip/hip_bf16.h>
#include <hip/hip_fp16.h>
#include <math.h>

#define N_NODES 10000
#define N_EDGES 160000
#define E_TOT   (N_EDGES + N_NODES)
#define F_IN    300
#define D       1024
#define N_CLS   10
#define NEG_SLOPE 0.2f

#define MP      10112              // 79 * 128, padded M
#define KP1     320                // F_IN padded to mult of 32
#define KP2     1024

typedef __attribute__((ext_vector_type(8))) _Float16 f16x8;
typedef __attribute__((ext_vector_type(4))) _Float16 f16x4;
typedef __attribute__((ext_vector_type(4))) float f32x4;

#define GLOAD_LDS16(g, l) __builtin_amdgcn_global_load_lds( \
    (const __attribute__((address_space(1))) void*)(g), \
    (__attribute__((address_space(3))) void*)(l), 16, 0, 0)

// ---------------- CSR build ----------------

__global__ void init_deg(int* __restrict__ deg) {
    int i = blockIdx.x * blockDim.x + threadIdx.x;
    if (i < N_NODES) deg[i] = 1;  // self loop
}

__global__ void count_edges(const int* __restrict__ dst, int* __restrict__ deg) {
    int e = blockIdx.x * blockDim.x + threadIdx.x;
    if (e < N_EDGES) atomicAdd(&deg[dst[e]], 1);
}

__global__ void scan_offs(const int* __restrict__ deg, int* __restrict__ offs,
                          int* __restrict__ pos) {
    __shared__ int sbuf[1024];
    __shared__ int scarry;
    int t = threadIdx.x;
    if (t == 0) { scarry = 0; offs[0] = 0; }
    __syncthreads();
    for (int base = 0; base < N_NODES; base += 1024) {
        int v = (base + t < N_NODES) ? deg[base + t] : 0;
        sbuf[t] = v;
        __syncthreads();
        for (int off = 1; off < 1024; off <<= 1) {
            int add = (t >= off) ? sbuf[t - off] : 0;
            __syncthreads();
            sbuf[t] += add;
            __syncthreads();
        }
        int carry = scarry;
        if (base + t < N_NODES) {
            int incl = carry + sbuf[t];
            offs[base + t + 1] = incl;
            pos[base + t]      = incl - v;
        }
        __syncthreads();
        if (t == 1023) scarry = carry + sbuf[1023];
        __syncthreads();
    }
}

__global__ void scatter_edges(const int* __restrict__ src, const int* __restrict__ dst,
                              int* __restrict__ pos, int* __restrict__ ssrc) {
    int e = blockIdx.x * blockDim.x + threadIdx.x;
    if (e < N_EDGES) {
        int d = dst[e];
        int p = atomicAdd(&pos[d], 1);
        ssrc[p] = src[e];
    } else if (e < E_TOT) {
        int i = e - N_EDGES;
        int p = atomicAdd(&pos[i], 1);
        ssrc[p] = i;
    }
}

// ---------------- projected attention vectors: u = W @ a_src, v = W @ a_dst ----------------

__global__ void prep_uv(const float* __restrict__ W1, const float* __restrict__ as1,
                        const float* __restrict__ ad1, const float* __restrict__ W2,
                        const float* __restrict__ as2, const float* __restrict__ ad2,
                        float* __restrict__ u1, float* __restrict__ v1,
                        float* __restrict__ u2, float* __restrict__ v2) {
    int wid  = (int)((blockIdx.x * blockDim.x + threadIdx.x) >> 6);
    int lane = threadIdx.x & 63;
    const float* row;
    const float* a;
    const float* b;
    float *du, *dv;
    int k;
    if (wid < F_IN) {
        k = wid; row = W1 + (size_t)k * D; a = as1; b = ad1; du = u1; dv = v1;
    } else if (wid < F_IN + D) {
        k = wid - F_IN; row = W2 + (size_t)k * D; a = as2; b = ad2; du = u2; dv = v2;
    } else return;
    float s1 = 0.f, s2 = 0.f;
    for (int n = lane; n < D; n += 64) {
        float w = row[n];
        s1 += w * a[n];
        s2 += w * b[n];
    }
    #pragma unroll
    for (int o = 32; o; o >>= 1) { s1 += __shfl_xor(s1, o); s2 += __shfl_xor(s2, o); }
    if (lane == 0) { du[k] = s1; dv[k] = s2; }
}

// ---------------- layer-1 node scores: hs1[i] = x_i . u1, hd1[i] = x_i . v1 ----------------

__global__ void node_scores_x(const float* __restrict__ x, const float* __restrict__ u1,
                              const float* __restrict__ v1, float* __restrict__ hs,
                              float* __restrict__ hd) {
    int wid  = (int)((blockIdx.x * blockDim.x + threadIdx.x) >> 6);
    int lane = threadIdx.x & 63;
    if (wid >= N_NODES) return;
    const float* row = x + (size_t)wid * F_IN;
    float s1 = 0.f, s2 = 0.f;
    for (int k = lane; k < F_IN; k += 64) {
        float v = row[k];
        s1 += v * u1[k];
        s2 += v * v1[k];
    }
    #pragma unroll
    for (int o = 32; o; o >>= 1) { s1 += __shfl_xor(s1, o); s2 += __shfl_xor(s2, o); }
    if (lane == 0) { hs[wid] = s1; hd[wid] = s2; }
}

// ---------------- zero hs2/hd2 + pad regions of the A-split buffers ----------------

#define ZR1 (112 * KP1)        // asplit1 pad rows, per plane
#define ZR2 (N_NODES * 20)     // asplit1 pad cols (300..319), per plane
#define ZR3 (112 * KP2)        // asplit2 pad rows, per plane
#define ZTOT (2*ZR1 + 2*ZR2 + 2*ZR3 + 2*N_NODES)

__global__ void zero_misc(float* __restrict__ hs2, float* __restrict__ hd2,
                          unsigned short* __restrict__ Ah1, unsigned short* __restrict__ Al1,
                          unsigned short* __restrict__ Ah2, unsigned short* __restrict__ Al2) {
    int idx = blockIdx.x * blockDim.x + threadIdx.x;
    if (idx >= ZTOT) return;
    if (idx < 2 * ZR1) {
        unsigned short* B = (idx < ZR1) ? Ah1 : Al1;
        int off = (idx < ZR1) ? idx : idx - ZR1;
        B[(size_t)N_NODES * KP1 + off] = 0;
    } else if ((idx -= 2 * ZR1) < 2 * ZR2) {
        unsigned short* B = (idx < ZR2) ? Ah1 : Al1;
        int off = (idx < ZR2) ? idx : idx - ZR2;
        int r = off / 20, c = 300 + off % 20;
        B[(size_t)r * KP1 + c] = 0;
    } else if ((idx -= 2 * ZR2) < 2 * ZR3) {
        unsigned short* B = (idx < ZR3) ? Ah2 : Al2;
        int off = (idx < ZR3) ? idx : idx - ZR3;
        B[(size_t)N_NODES * KP2 + off] = 0;
    } else {
        idx -= 2 * ZR3;
        if (idx < N_NODES) hs2[idx] = 0.f;
        else hd2[idx - N_NODES] = 0.f;
    }
}

// ---------------- transpose W [K][N] -> BT [N][Kp] (single fp16 plane) ----------------

__global__ void transpose_f16(const float* __restrict__ W, _Float16* __restrict__ BTh,
                              int K, int N, int Kp) {
    __shared__ float tile[32][33];
    int k0 = blockIdx.x * 32, n0 = blockIdx.y * 32;
    int tx = threadIdx.x, ty = threadIdx.y;
    #pragma unroll
    for (int j = 0; j < 32; j += 8) {
        int k = k0 + ty + j;
        tile[ty + j][tx] = (k < K) ? W[(size_t)k * N + n0 + tx] : 0.f;
    }
    __syncthreads();
    #pragma unroll
    for (int j = 0; j < 32; j += 8) {
        int n = n0 + ty + j;
        int k = k0 + tx;
        BTh[(size_t)n * Kp + k] = (_Float16)tile[tx][ty + j];
    }
}

// ---------------- layer-1 aggregate over raw x (300-wide) ----------------
// agg[i] = (1/denom) * sum_j exp(e_ij - m) * x_j ; output hi/lo fp16 planes
// [MP][KP1]. 3 edge-groups x 75 lanes (75 float4 slots per row), 2-deep unroll.

__global__ __launch_bounds__(256) void aggregate_x(
        const float* __restrict__ x, const float* __restrict__ hs,
        const float* __restrict__ hd, const int* __restrict__ offs,
        const int* __restrict__ ssrc, _Float16* __restrict__ outh,
        _Float16* __restrict__ outl) {
    int i = blockIdx.x;
    int t = threadIdx.x;
    int lane = t & 63;
    int wv = t >> 6;
    int start = offs[i], end = offs[i + 1];
    __shared__ float red[8];
    __shared__ float part[2][75][4];
    float hdi = hd[i];

    // block max
    float lmax = -INFINITY;
    for (int p = start + t; p < end; p += 256) {
        float s = hs[ssrc[p]] + hdi;
        s = (s >= 0.f) ? s : s * NEG_SLOPE;
        lmax = fmaxf(lmax, s);
    }
    #pragma unroll
    for (int o = 32; o; o >>= 1) lmax = fmaxf(lmax, __shfl_xor(lmax, o));
    if (lane == 0) red[wv] = lmax;
    __syncthreads();
    float m = fmaxf(fmaxf(red[0], red[1]), fmaxf(red[2], red[3]));

    // block sum of exp
    float lsum = 0.f;
    for (int p = start + t; p < end; p += 256) {
        float s = hs[ssrc[p]] + hdi;
        s = (s >= 0.f) ? s : s * NEG_SLOPE;
        lsum += __expf(s - m);
    }
    #pragma unroll
    for (int o = 32; o; o >>= 1) lsum += __shfl_xor(lsum, o);
    if (lane == 0) red[4 + wv] = lsum;
    __syncthreads();
    float inv = 1.0f / (red[4] + red[5] + red[6] + red[7]);

    // weighted gather over x rows, 3 groups x 75 slots
    int g = t / 75;
    int s = t - g * 75;
    int c = s * 4;
    float4 a = {0.f, 0.f, 0.f, 0.f};
    if (t < 225) {
        int p = start + g;
        for (; p + 3 < end; p += 6) {
            int j0 = ssrc[p], j1 = ssrc[p + 3];
            float s0 = hs[j0] + hdi; s0 = (s0 >= 0.f) ? s0 : s0 * NEG_SLOPE;
            float s1 = hs[j1] + hdi; s1 = (s1 >= 0.f) ? s1 : s1 * NEG_SLOPE;
            float w0 = __expf(s0 - m), w1 = __expf(s1 - m);
            float4 v0 = *(const float4*)(x + (size_t)j0 * F_IN + c);
            float4 v1 = *(const float4*)(x + (size_t)j1 * F_IN + c);
            a.x += w0 * v0.x + w1 * v1.x;
            a.y += w0 * v0.y + w1 * v1.y;
            a.z += w0 * v0.z + w1 * v1.z;
            a.w += w0 * v0.w + w1 * v1.w;
        }
        if (p < end) {
            int j0 = ssrc[p];
            float s0 = hs[j0] + hdi; s0 = (s0 >= 0.f) ? s0 : s0 * NEG_SLOPE;
            float w0 = __expf(s0 - m);
            float4 v0 = *(const float4*)(x + (size_t)j0 * F_IN + c);
            a.x += w0 * v0.x; a.y += w0 * v0.y; a.z += w0 * v0.z; a.w += w0 * v0.w;
        }
    }
    if (t < 225 && g > 0) {
        part[g - 1][s][0] = a.x; part[g - 1][s][1] = a.y;
        part[g - 1][s][2] = a.z; part[g - 1][s][3] = a.w;
    }
    __syncthreads();
    if (t < 75) {
        a.x += part[0][t][0] + part[1][t][0];
        a.y += part[0][t][1] + part[1][t][1];
        a.z += part[0][t][2] + part[1][t][2];
        a.w += part[0][t][3] + part[1][t][3];
        float rv[4] = {a.x * inv, a.y * inv, a.z * inv, a.w * inv};
        _Float16 hi4[4], lo4[4];
        #pragma unroll
        for (int q = 0; q < 4; ++q) {
            _Float16 hi = (_Float16)rv[q];
            hi4[q] = hi;
            lo4[q] = (_Float16)(rv[q] - (float)hi);
        }
        *(float2*)(outh + (size_t)i * KP1 + c) = *(float2*)hi4;
        *(float2*)(outl + (size_t)i * KP1 + c) = *(float2*)lo4;
    }
}

// ---------------- layer-2 aggregate over fp16 emb1 (1024-wide) ----------------
// gathers f16x4 (8B/lane) from the 20 MB fp16 emb1 -> half the gather traffic
// of fp32. Accumulate fp32; output hi/lo fp16 planes [MP][KP2].

__global__ __launch_bounds__(256) void aggregate_d(
        const _Float16* __restrict__ h, const float* __restrict__ hs,
        const float* __restrict__ hd, const int* __restrict__ offs,
        const int* __restrict__ ssrc, _Float16* __restrict__ outh,
        _Float16* __restrict__ outl) {
    int i = blockIdx.x;
    int t = threadIdx.x;
    int lane = t & 63;
    int wv = t >> 6;
    int start = offs[i], end = offs[i + 1];
    __shared__ float red[8];
    float hdi = hd[i];

    float lmax = -INFINITY;
    for (int p = start + t; p < end; p += 256) {
        float s = hs[ssrc[p]] + hdi;
        s = (s >= 0.f) ? s : s * NEG_SLOPE;
        lmax = fmaxf(lmax, s);
    }
    #pragma unroll
    for (int o = 32; o; o >>= 1) lmax = fmaxf(lmax, __shfl_xor(lmax, o));
    if (lane == 0) red[wv] = lmax;
    __syncthreads();
    float m = fmaxf(fmaxf(red[0], red[1]), fmaxf(red[2], red[3]));

    float lsum = 0.f;
    for (int p = start + t; p < end; p += 256) {
        float s = hs[ssrc[p]] + hdi;
        s = (s >= 0.f) ? s : s * NEG_SLOPE;
        lsum += __expf(s - m);
    }
    #pragma unroll
    for (int o = 32; o; o >>= 1) lsum += __shfl_xor(lsum, o);
    if (lane == 0) red[4 + wv] = lsum;
    __syncthreads();
    float inv = 1.0f / (red[4] + red[5] + red[6] + red[7]);

    int c = t * 4;
    float4 a0 = {0.f,0.f,0.f,0.f}, a1 = a0, a2 = a0, a3 = a0;
    int p = start;
    for (; p + 4 <= end; p += 4) {
        int j0 = ssrc[p], j1 = ssrc[p+1], j2 = ssrc[p+2], j3 = ssrc[p+3];
        float s0 = hs[j0] + hdi; s0 = (s0 >= 0.f) ? s0 : s0 * NEG_SLOPE;
        float s1 = hs[j1] + hdi; s1 = (s1 >= 0.f) ? s1 : s1 * NEG_SLOPE;
        float s2 = hs[j2] + hdi; s2 = (s2 >= 0.f) ? s2 : s2 * NEG_SLOPE;
        float s3 = hs[j3] + hdi; s3 = (s3 >= 0.f) ? s3 : s3 * NEG_SLOPE;
        float w0 = __expf(s0 - m), w1 = __expf(s1 - m);
        float w2 = __expf(s2 - m), w3 = __expf(s3 - m);
        f16x4 v0 = *(const f16x4*)(h + (size_t)j0 * D + c);
        f16x4 v1 = *(const f16x4*)(h + (size_t)j1 * D + c);
        f16x4 v2 = *(const f16x4*)(h + (size_t)j2 * D + c);
        f16x4 v3 = *(const f16x4*)(h + (size_t)j3 * D + c);
        a0.x += w0*(float)v0.x; a0.y += w0*(float)v0.y; a0.z += w0*(float)v0.z; a0.w += w0*(float)v0.w;
        a1.x += w1*(float)v1.x; a1.y += w1*(float)v1.y; a1.z += w1*(float)v1.z; a1.w += w1*(float)v1.w;
        a2.x += w2*(float)v2.x; a2.y += w2*(float)v2.y; a2.z += w2*(float)v2.z; a2.w += w2*(float)v2.w;
        a3.x += w3*(float)v3.x; a3.y += w3*(float)v3.y; a3.z += w3*(float)v3.z; a3.w += w3*(float)v3.w;
    }
    for (; p < end; ++p) {
        int j0 = ssrc[p];
        float s0 = hs[j0] + hdi; s0 = (s0 >= 0.f) ? s0 : s0 * NEG_SLOPE;
        float w0 = __expf(s0 - m);
        f16x4 v0 = *(const f16x4*)(h + (size_t)j0 * D + c);
        a0.x += w0*(float)v0.x; a0.y += w0*(float)v0.y; a0.z += w0*(float)v0.z; a0.w += w0*(float)v0.w;
    }
    float rv[4];
    rv[0] = ((a0.x + a1.x) + (a2.x + a3.x)) * inv;
    rv[1] = ((a0.y + a1.y) + (a2.y + a3.y)) * inv;
    rv[2] = ((a0.z + a1.z) + (a2.z + a3.z)) * inv;
    rv[3] = ((a0.w + a1.w) + (a2.w + a3.w)) * inv;
    _Float16 hi4[4], lo4[4];
    #pragma unroll
    for (int q = 0; q < 4; ++q) {
        _Float16 hi = (_Float16)rv[q];
        hi4[q] = hi;
        lo4[q] = (_Float16)(rv[q] - (float)hi);
    }
    *(float2*)(outh + (size_t)i * KP2 + c) = *(float2*)hi4;
    *(float2*)(outl + (size_t)i * KP2 + c) = *(float2*)lo4;
}

// ---------------- split-fp16 MFMA GEMM, 2-phase double-buffered, BK=32 ----------------
// C = relu((Ah+Al)@Bh^T + bias). Next K-step's global_load_lds issued BEFORE
// the current step's ds_read+MFMA; the trailing __syncthreads (vmcnt0+barrier)
// is exactly the required drain -> staging overlaps compute (grid-limited
// occupancy means TLP alone can't hide it). Cf (fp32) or Ch (fp16) output.

__global__ __launch_bounds__(256) void gemm_split_mfma(
        const _Float16* __restrict__ Ah, const _Float16* __restrict__ Al,
        const _Float16* __restrict__ BTh,
        float* __restrict__ Cf, _Float16* __restrict__ Ch,
        const float* __restrict__ bias,
        const float* __restrict__ asrc, const float* __restrict__ adst,
        float* __restrict__ hs, float* __restrict__ hd,
        int Mreal, int Kp, int dots) {
    __shared__ char lds[49152];              // 2 x {Ah 8K | Al 8K | Bh 8K}
    const int t    = threadIdx.x;
    const int lane = t & 63;
    const int wid  = t >> 6;
    const int chunkg = (int)gridDim.x >> 3;
    const int vid  = ((int)blockIdx.x & 7) * chunkg + ((int)blockIdx.x >> 3);
    const int n0 = (vid & 7) * 128;
    const int m0 = (vid >> 3) * 128;
    const int wr = (wid >> 1) * 64;
    const int wc = (wid & 1) * 64;
    const int fr = lane & 15;
    const int kg = lane >> 4;

    const int r0 = t >> 2, s0 = t & 3;
    const int r1 = r0 + 64;
    const int g0 = (s0 ^ ((r0 >> 1) & 3)) << 3;
    const int g1 = (s0 ^ ((r1 >> 1) & 3)) << 3;
    const size_t oA0 = (size_t)(m0 + r0) * Kp + g0;
    const size_t oA1 = (size_t)(m0 + r1) * Kp + g1;
    const size_t oB0 = (size_t)(n0 + r0) * Kp + g0;
    const size_t oB1 = (size_t)(n0 + r1) * Kp + g1;
    const int ko = (kg ^ ((fr >> 1) & 3)) << 4;

    f32x4 acc[4][4] = {};

    auto STAGE = [&](int b, int kb) {
        char* base = lds + b * 24576;
        GLOAD_LDS16(Ah  + oA0 + kb, base + t * 16);
        GLOAD_LDS16(Ah  + oA1 + kb, base + 4096  + t * 16);
        GLOAD_LDS16(Al  + oA0 + kb, base + 8192  + t * 16);
        GLOAD_LDS16(Al  + oA1 + kb, base + 12288 + t * 16);
        GLOAD_LDS16(BTh + oB0 + kb, base + 16384 + t * 16);
        GLOAD_LDS16(BTh + oB1 + kb, base + 20480 + t * 16);
    };

    STAGE(0, 0);
    __syncthreads();

    int cur = 0;
    for (int kb = 0; kb < Kp; kb += 32) {
        if (kb + 32 < Kp) STAGE(cur ^ 1, kb + 32);   // prefetch overlaps compute
        char* base = lds + cur * 24576;
        f16x8 ah[4], al[4], bh[4];
        #pragma unroll
        for (int f = 0; f < 4; ++f) {
            int ra = (wr + f * 16 + fr) * 64 + ko;
            int rb = (wc + f * 16 + fr) * 64 + ko;
            ah[f] = *(const f16x8*)(base + ra);
            al[f] = *(const f16x8*)(base + 8192 + ra);
            bh[f] = *(const f16x8*)(base + 16384 + rb);
        }
        #pragma unroll
        for (int fm = 0; fm < 4; ++fm)
            #pragma unroll
            for (int fn = 0; fn < 4; ++fn)
                acc[fm][fn] = __builtin_amdgcn_mfma_f32_16x16x32_f16(
                    ah[fm], bh[fn], acc[fm][fn], 0, 0, 0);
        #pragma unroll
        for (int fm = 0; fm < 4; ++fm)
            #pragma unroll
            for (int fn = 0; fn < 4; ++fn)
                acc[fm][fn] = __builtin_amdgcn_mfma_f32_16x16x32_f16(
                    al[fm], bh[fn], acc[fm][fn], 0, 0, 0);
        __syncthreads();   // drains prefetch (vmcnt0) + syncs reads of buf cur
        cur ^= 1;
    }

    // epilogue: bias + relu; write fp32 (Cf) or fp16 (Ch)
    float bv[4];
    #pragma unroll
    for (int fn = 0; fn < 4; ++fn) bv[fn] = bias[n0 + wc + fn * 16 + fr];
    #pragma unroll
    for (int fm = 0; fm < 4; ++fm) {
        int mb = m0 + wr + fm * 16 + kg * 4;
        #pragma unroll
        for (int fn = 0; fn < 4; ++fn) {
            int cn = n0 + wc + fn * 16 + fr;
            #pragma unroll
            for (int j = 0; j < 4; ++j) {
                float r = fmaxf(acc[fm][fn][j] + bv[fn], 0.f);
                acc[fm][fn][j] = r;
                int m = mb + j;
                if (m < Mreal) {
                    if (Cf) Cf[(size_t)m * 1024 + cn] = r;
                    else    Ch[(size_t)m * 1024 + cn] = (_Float16)r;
                }
            }
        }
    }

    if (dots) {
        float av[4], dv[4];
        #pragma unroll
        for (int fn = 0; fn < 4; ++fn) {
            int cn = n0 + wc + fn * 16 + fr;
            av[fn] = asrc[cn];
            dv[fn] = adst[cn];
        }
        #pragma unroll
        for (int fm = 0; fm < 4; ++fm) {
            #pragma unroll
            for (int j = 0; j < 4; ++j) {
                float v1 = acc[fm][0][j] * av[0] + acc[fm][1][j] * av[1]
                         + acc[fm][2][j] * av[2] + acc[fm][3][j] * av[3];
                float v2 = acc[fm][0][j] * dv[0] + acc[fm][1][j] * dv[1]
                         + acc[fm][2][j] * dv[2] + acc[fm][3][j] * dv[3];
                #pragma unroll
                for (int o = 1; o < 16; o <<= 1) {
                    v1 += __shfl_xor(v1, o);
                    v2 += __shfl_xor(v2, o);
                }
                int m = m0 + wr + fm * 16 + kg * 4 + j;
                if (fr == 0 && m < Mreal) {
                    atomicAdd(&hs[m], v1);
                    atomicAdd(&hd[m], v2);
                }
            }
        }
    }
}

// ---------------- final fc + softmax ----------------

__global__ void fc_softmax(const float* __restrict__ emb, const float* __restrict__ fcw,
                           const float* __restrict__ fcb, float* __restrict__ out) {
    int wid  = (int)((blockIdx.x * blockDim.x + threadIdx.x) >> 6);
    int lane = threadIdx.x & 63;
    if (wid >= N_NODES) return;
    float acc[N_CLS] = {};
    const float* row = emb + (size_t)wid * D;
    for (int k = lane * 4; k < D; k += 256) {
        float4 v = *(const float4*)(row + k);
        #pragma unroll
        for (int c = 0; c < N_CLS; ++c)
            acc[c] += v.x * fcw[k * N_CLS + c] + v.y * fcw[(k+1) * N_CLS + c]
                    + v.z * fcw[(k+2) * N_CLS + c] + v.w * fcw[(k+3) * N_CLS + c];
    }
    #pragma unroll
    for (int c = 0; c < N_CLS; ++c) {
        #pragma unroll
        for (int o = 32; o; o >>= 1) acc[c] += __shfl_xor(acc[c], o);
    }
    if (lane == 0) {
        float logit[N_CLS];
        float m = -INFINITY;
        #pragma unroll
        for (int c = 0; c < N_CLS; ++c) { logit[c] = acc[c] + fcb[c]; m = fmaxf(m, logit[c]); }
        float s = 0.f;
        #pragma unroll
        for (int c = 0; c < N_CLS; ++c) { logit[c] = __expf(logit[c] - m); s += logit[c]; }
        float invs = 1.0f / s;
        #pragma unroll
        for (int c = 0; c < N_CLS; ++c) out[(size_t)wid * N_CLS + c] = logit[c] * invs;
    }
}

// ---------------- launch ----------------

extern "C" void kernel_launch(void* const* d_in, const int* in_sizes, int n_in,
                              void* d_out, int out_size, void* d_ws, size_t ws_size,
                              hipStream_t stream) {
    const float* x        = (const float*)d_in[0];
    const int*   ei       = (const int*)d_in[1];
    const float* W1       = (const float*)d_in[2];
    const float* att_src1 = (const float*)d_in[3];
    const float* att_dst1 = (const float*)d_in[4];
    const float* b1       = (const float*)d_in[5];
    const float* W2       = (const float*)d_in[6];
    const float* att_src2 = (const float*)d_in[7];
    const float* att_dst2 = (const float*)d_in[8];
    const float* b2       = (const float*)d_in[9];
    const float* fc_w     = (const float*)d_in[10];
    const float* fc_b     = (const float*)d_in[11];
    float* out = (float*)d_out;

    const int* src = ei;
    const int* dst = ei + N_EDGES;

    char* w = (char*)d_ws;
    #define ALLOC(name, bytes) char* name = w; w += (((size_t)(bytes) + 255) & ~(size_t)255)
    ALLOC(p_emb,   (size_t)N_NODES * D * 4);           // emb2 fp32 (fc input)
    ALLOC(p_embh,  (size_t)N_NODES * D * 2);           // emb1 fp16 (gather source)
    ALLOC(p_hs1,   (size_t)N_NODES * 4);
    ALLOC(p_hd1,   (size_t)N_NODES * 4);
    ALLOC(p_hs2,   (size_t)N_NODES * 4);
    ALLOC(p_hd2,   (size_t)N_NODES * 4);
    ALLOC(p_deg,   (size_t)N_NODES * 4);
    ALLOC(p_offs,  (size_t)(N_NODES + 1) * 4);
    ALLOC(p_pos,   (size_t)N_NODES * 4);
    ALLOC(p_ssrc,  (size_t)E_TOT * 4);
    ALLOC(p_u1,    (size_t)F_IN * 4);
    ALLOC(p_v1,    (size_t)F_IN * 4);
    ALLOC(p_u2,    (size_t)D * 4);
    ALLOC(p_v2,    (size_t)D * 4);
    ALLOC(p_as1,   (size_t)2 * MP * KP1 * 2);          // Ah1|Al1 fp16 planes
    ALLOC(p_as2,   (size_t)2 * MP * KP2 * 2);          // Ah2|Al2 fp16 planes
    ALLOC(p_bt1,   (size_t)D * KP1 * 2);               // BT1h fp16
    ALLOC(p_bt2,   (size_t)D * KP2 * 2);               // BT2h fp16
    #undef ALLOC

    float* emb  = (float*)p_emb;
    _Float16* embh = (_Float16*)p_embh;
    float* hs1  = (float*)p_hs1;
    float* hd1  = (float*)p_hd1;
    float* hs2  = (float*)p_hs2;
    float* hd2  = (float*)p_hd2;
    int*   deg  = (int*)p_deg;
    int*   offs = (int*)p_offs;
    int*   pos  = (int*)p_pos;
    int*   ssrc = (int*)p_ssrc;
    float* u1 = (float*)p_u1; float* v1 = (float*)p_v1;
    float* u2 = (float*)p_u2; float* v2 = (float*)p_v2;
    _Float16* Ah1  = (_Float16*)p_as1;
    _Float16* Al1  = Ah1 + (size_t)MP * KP1;
    _Float16* Ah2  = (_Float16*)p_as2;
    _Float16* Al2  = Ah2 + (size_t)MP * KP2;
    _Float16* BT1h = (_Float16*)p_bt1;
    _Float16* BT2h = (_Float16*)p_bt2;

    // CSR build
    init_deg<<<(N_NODES + 255) / 256, 256, 0, stream>>>(deg);
    count_edges<<<(N_EDGES + 255) / 256, 256, 0, stream>>>(dst, deg);
    scan_offs<<<1, 1024, 0, stream>>>(deg, offs, pos);
    scatter_edges<<<(E_TOT + 255) / 256, 256, 0, stream>>>(src, dst, pos, ssrc);

    // projected attention vectors + weight transposes + zero pads
    prep_uv<<<((F_IN + D) * 64 + 255) / 256, 256, 0, stream>>>(
        W1, att_src1, att_dst1, W2, att_src2, att_dst2, u1, v1, u2, v2);
    dim3 tb(32, 8);
    transpose_f16<<<dim3(KP1 / 32, D / 32), tb, 0, stream>>>(W1, BT1h, F_IN, D, KP1);
    transpose_f16<<<dim3(KP2 / 32, D / 32), tb, 0, stream>>>(W2, BT2h, D, D, KP2);
    zero_misc<<<(ZTOT + 255) / 256, 256, 0, stream>>>(hs2, hd2,
        (unsigned short*)Ah1, (unsigned short*)Al1,
        (unsigned short*)Ah2, (unsigned short*)Al2);

    const int gemmGrid = (D / 128) * (MP / 128);   // 632 = 8*79

    // layer 1: scores, aggregate x, GEMM -> fp16 emb1 (+b1, relu, fused layer-2 dots)
    node_scores_x<<<(N_NODES * 64 + 255) / 256, 256, 0, stream>>>(x, u1, v1, hs1, hd1);
    aggregate_x<<<N_NODES, 256, 0, stream>>>(x, hs1, hd1, offs, ssrc, Ah1, Al1);
    gemm_split_mfma<<<gemmGrid, 256, 0, stream>>>(Ah1, Al1, BT1h,
                                                  (float*)nullptr, embh, b1,
                                                  u2, v2, hs2, hd2, N_NODES, KP1, 1);

    // layer 2: aggregate fp16 emb1, GEMM -> fp32 emb2 (+b2, relu)
    aggregate_d<<<N_NODES, 256, 0, stream>>>(embh, hs2, hd2, offs, ssrc, Ah2, Al2);
    gemm_split_mfma<<<gemmGrid, 256, 0, stream>>>(Ah2, Al2, BT2h,
                                                  emb, (_Float16*)nullptr, b2,
                                                  (const float*)nullptr, (const float*)nullptr,
                                                  (float*)nullptr, (float*)nullptr,
                                                  N_NODES, KP2, 0);

    // classifier
    fc_softmax<<<(N_NODES * 64 + 255) / 256, 256, 0, stream>>>(emb, fc_w, fc_b, out);
}

// Round 12
// 332.261 us; speedup vs baseline: 1.3588x; 1.0186x over previous
//
#include <hip/hip_runtime.h>
#include <hip/hip_bf16.h>
#include <hip/hip_fp16.h>
#include <math.h>

#define N_NODES 10000
#define N_EDGES 160000
#define E_TOT   (N_EDGES + N_NODES)
#define F_IN    300
#define D       1024
#define N_CLS   10
#define NEG_SLOPE 0.2f

#define MP      10112              // 79 * 128, padded M
#define KP1     320                // F_IN padded to mult of 32
#define KP2     1024

typedef __attribute__((ext_vector_type(8))) _Float16 f16x8;
typedef __attribute__((ext_vector_type(4))) float f32x4;

#define GLOAD_LDS16(g, l) __builtin_amdgcn_global_load_lds( \
    (const __attribute__((address_space(1))) void*)(g), \
    (__attribute__((address_space(3))) void*)(l), 16, 0, 0)

// ---------------- CSR build (count/scan/scatter; deg init in mega_prep) ----------------

__global__ void count_edges(const int* __restrict__ dst, int* __restrict__ deg) {
    int e = blockIdx.x * blockDim.x + threadIdx.x;
    if (e < N_EDGES) atomicAdd(&deg[dst[e]], 1);
}

__global__ void scan_offs(const int* __restrict__ deg, int* __restrict__ offs,
                          int* __restrict__ pos) {
    __shared__ int sbuf[1024];
    __shared__ int scarry;
    int t = threadIdx.x;
    if (t == 0) { scarry = 0; offs[0] = 0; }
    __syncthreads();
    for (int base = 0; base < N_NODES; base += 1024) {
        int v = (base + t < N_NODES) ? deg[base + t] : 0;
        sbuf[t] = v;
        __syncthreads();
        for (int off = 1; off < 1024; off <<= 1) {
            int add = (t >= off) ? sbuf[t - off] : 0;
            __syncthreads();
            sbuf[t] += add;
            __syncthreads();
        }
        int carry = scarry;
        if (base + t < N_NODES) {
            int incl = carry + sbuf[t];
            offs[base + t + 1] = incl;
            pos[base + t]      = incl - v;
        }
        __syncthreads();
        if (t == 1023) scarry = carry + sbuf[1023];
        __syncthreads();
    }
}

__global__ void scatter_edges(const int* __restrict__ src, const int* __restrict__ dst,
                              int* __restrict__ pos, int* __restrict__ ssrc) {
    int e = blockIdx.x * blockDim.x + threadIdx.x;
    if (e < N_EDGES) {
        int d = dst[e];
        int p = atomicAdd(&pos[d], 1);
        ssrc[p] = src[e];
    } else if (e < E_TOT) {
        int i = e - N_EDGES;
        int p = atomicAdd(&pos[i], 1);
        ssrc[p] = i;
    }
}

// ---------------- mega_prep: prep_uv | transpose W1 | transpose W2 | zeros+deg ----------------

#define ZR1 (112 * KP1)        // asplit1 pad rows, per plane
#define ZR2 (N_NODES * 20)     // asplit1 pad cols (300..319), per plane
#define ZR3 (112 * KP2)        // asplit2 pad rows, per plane
#define ZTOT (2*ZR1 + 2*ZR2 + 2*ZR3 + 2*N_NODES)

#define ZONE_A 331             // prep_uv: (F_IN+D)*64/256 waves
#define ZONE_B 320             // transpose W1: (KP1/32)*(D/32)
#define ZONE_C 1024            // transpose W2: (KP2/32)*(D/32)
#define ZONE_D ((ZTOT + N_NODES + 255) / 256)

__global__ __launch_bounds__(256) void mega_prep(
        const float* __restrict__ W1, const float* __restrict__ as1,
        const float* __restrict__ ad1, const float* __restrict__ W2,
        const float* __restrict__ as2, const float* __restrict__ ad2,
        float* __restrict__ u1, float* __restrict__ v1,
        float* __restrict__ u2, float* __restrict__ v2,
        _Float16* __restrict__ BT1h, _Float16* __restrict__ BT2h,
        float* __restrict__ hs2, float* __restrict__ hd2,
        unsigned short* __restrict__ Ah1, unsigned short* __restrict__ Al1,
        unsigned short* __restrict__ Ah2, unsigned short* __restrict__ Al2,
        int* __restrict__ deg) {
    __shared__ float tile[32][33];
    int b = blockIdx.x;
    int t = threadIdx.x;

    if (b < ZONE_A) {
        // prep_uv: u = W @ a_src, v = W @ a_dst (one wave per W row)
        int wid  = (b * 256 + t) >> 6;
        int lane = t & 63;
        const float* row; const float* a; const float* bb; float *du, *dv; int k;
        if (wid < F_IN) {
            k = wid; row = W1 + (size_t)k * D; a = as1; bb = ad1; du = u1; dv = v1;
        } else {
            k = wid - F_IN; row = W2 + (size_t)k * D; a = as2; bb = ad2; du = u2; dv = v2;
        }
        float s1 = 0.f, s2 = 0.f;
        for (int n = lane; n < D; n += 64) {
            float w = row[n];
            s1 += w * a[n];
            s2 += w * bb[n];
        }
        #pragma unroll
        for (int o = 32; o; o >>= 1) { s1 += __shfl_xor(s1, o); s2 += __shfl_xor(s2, o); }
        if (lane == 0) { du[k] = s1; dv[k] = s2; }
        return;
    }
    if (b < ZONE_A + ZONE_B + ZONE_C) {
        // transpose+fp16 of W1 or W2
        const float* W; _Float16* BT; int K, Kp, b2;
        if (b < ZONE_A + ZONE_B) { b2 = b - ZONE_A; W = W1; BT = BT1h; K = F_IN; Kp = KP1;
            int kb = b2 % (KP1 / 32), nb = b2 / (KP1 / 32);
            int k0 = kb * 32, n0 = nb * 32;
            int tx = t & 31, ty = t >> 5;
            #pragma unroll
            for (int j = 0; j < 32; j += 8) {
                int k = k0 + ty + j;
                tile[ty + j][tx] = (k < K) ? W[(size_t)k * D + n0 + tx] : 0.f;
            }
            __syncthreads();
            #pragma unroll
            for (int j = 0; j < 32; j += 8)
                BT[(size_t)(n0 + ty + j) * Kp + k0 + tx] = (_Float16)tile[tx][ty + j];
        } else { b2 = b - ZONE_A - ZONE_B; W = W2; BT = BT2h; K = D; Kp = KP2;
            int kb = b2 & 31, nb = b2 >> 5;
            int k0 = kb * 32, n0 = nb * 32;
            int tx = t & 31, ty = t >> 5;
            #pragma unroll
            for (int j = 0; j < 32; j += 8) {
                int k = k0 + ty + j;
                tile[ty + j][tx] = (k < K) ? W[(size_t)k * D + n0 + tx] : 0.f;
            }
            __syncthreads();
            #pragma unroll
            for (int j = 0; j < 32; j += 8)
                BT[(size_t)(n0 + ty + j) * Kp + k0 + tx] = (_Float16)tile[tx][ty + j];
        }
        return;
    }
    // zone D: zeros + deg init
    int idx = (b - ZONE_A - ZONE_B - ZONE_C) * 256 + t;
    if (idx >= ZTOT + N_NODES) return;
    if (idx >= ZTOT) { deg[idx - ZTOT] = 1; return; }   // self loop
    if (idx < 2 * ZR1) {
        unsigned short* B = (idx < ZR1) ? Ah1 : Al1;
        int off = (idx < ZR1) ? idx : idx - ZR1;
        B[(size_t)N_NODES * KP1 + off] = 0;
    } else if ((idx -= 2 * ZR1) < 2 * ZR2) {
        unsigned short* B = (idx < ZR2) ? Ah1 : Al1;
        int off = (idx < ZR2) ? idx : idx - ZR2;
        int r = off / 20, c = 300 + off % 20;
        B[(size_t)r * KP1 + c] = 0;
    } else if ((idx -= 2 * ZR2) < 2 * ZR3) {
        unsigned short* B = (idx < ZR3) ? Ah2 : Al2;
        int off = (idx < ZR3) ? idx : idx - ZR3;
        B[(size_t)N_NODES * KP2 + off] = 0;
    } else {
        idx -= 2 * ZR3;
        if (idx < N_NODES) hs2[idx] = 0.f;
        else hd2[idx - N_NODES] = 0.f;
    }
}

// ---------------- layer-1 node scores: hs1[i] = x_i . u1, hd1[i] = x_i . v1 ----------------

__global__ void node_scores_x(const float* __restrict__ x, const float* __restrict__ u1,
                              const float* __restrict__ v1, float* __restrict__ hs,
                              float* __restrict__ hd) {
    int wid  = (int)((blockIdx.x * blockDim.x + threadIdx.x) >> 6);
    int lane = threadIdx.x & 63;
    if (wid >= N_NODES) return;
    const float* row = x + (size_t)wid * F_IN;
    float s1 = 0.f, s2 = 0.f;
    for (int k = lane; k < F_IN; k += 64) {
        float v = row[k];
        s1 += v * u1[k];
        s2 += v * v1[k];
    }
    #pragma unroll
    for (int o = 32; o; o >>= 1) { s1 += __shfl_xor(s1, o); s2 += __shfl_xor(s2, o); }
    if (lane == 0) { hs[wid] = s1; hd[wid] = s2; }
}

// ---------------- layer-1 aggregate over raw x (300-wide) ----------------

__global__ __launch_bounds__(256) void aggregate_x(
        const float* __restrict__ x, const float* __restrict__ hs,
        const float* __restrict__ hd, const int* __restrict__ offs,
        const int* __restrict__ ssrc, _Float16* __restrict__ outh,
        _Float16* __restrict__ outl) {
    int i = blockIdx.x;
    int t = threadIdx.x;
    int lane = t & 63;
    int wv = t >> 6;
    int start = offs[i], end = offs[i + 1];
    __shared__ float red[8];
    __shared__ float part[2][75][4];
    float hdi = hd[i];

    float lmax = -INFINITY;
    for (int p = start + t; p < end; p += 256) {
        float s = hs[ssrc[p]] + hdi;
        s = (s >= 0.f) ? s : s * NEG_SLOPE;
        lmax = fmaxf(lmax, s);
    }
    #pragma unroll
    for (int o = 32; o; o >>= 1) lmax = fmaxf(lmax, __shfl_xor(lmax, o));
    if (lane == 0) red[wv] = lmax;
    __syncthreads();
    float m = fmaxf(fmaxf(red[0], red[1]), fmaxf(red[2], red[3]));

    float lsum = 0.f;
    for (int p = start + t; p < end; p += 256) {
        float s = hs[ssrc[p]] + hdi;
        s = (s >= 0.f) ? s : s * NEG_SLOPE;
        lsum += __expf(s - m);
    }
    #pragma unroll
    for (int o = 32; o; o >>= 1) lsum += __shfl_xor(lsum, o);
    if (lane == 0) red[4 + wv] = lsum;
    __syncthreads();
    float inv = 1.0f / (red[4] + red[5] + red[6] + red[7]);

    int g = t / 75;
    int s = t - g * 75;
    int c = s * 4;
    float4 a = {0.f, 0.f, 0.f, 0.f};
    if (t < 225) {
        int p = start + g;
        for (; p + 3 < end; p += 6) {
            int j0 = ssrc[p], j1 = ssrc[p + 3];
            float s0 = hs[j0] + hdi; s0 = (s0 >= 0.f) ? s0 : s0 * NEG_SLOPE;
            float s1 = hs[j1] + hdi; s1 = (s1 >= 0.f) ? s1 : s1 * NEG_SLOPE;
            float w0 = __expf(s0 - m), w1 = __expf(s1 - m);
            float4 v0 = *(const float4*)(x + (size_t)j0 * F_IN + c);
            float4 v1 = *(const float4*)(x + (size_t)j1 * F_IN + c);
            a.x += w0 * v0.x + w1 * v1.x;
            a.y += w0 * v0.y + w1 * v1.y;
            a.z += w0 * v0.z + w1 * v1.z;
            a.w += w0 * v0.w + w1 * v1.w;
        }
        if (p < end) {
            int j0 = ssrc[p];
            float s0 = hs[j0] + hdi; s0 = (s0 >= 0.f) ? s0 : s0 * NEG_SLOPE;
            float w0 = __expf(s0 - m);
            float4 v0 = *(const float4*)(x + (size_t)j0 * F_IN + c);
            a.x += w0 * v0.x; a.y += w0 * v0.y; a.z += w0 * v0.z; a.w += w0 * v0.w;
        }
    }
    if (t < 225 && g > 0) {
        part[g - 1][s][0] = a.x; part[g - 1][s][1] = a.y;
        part[g - 1][s][2] = a.z; part[g - 1][s][3] = a.w;
    }
    __syncthreads();
    if (t < 75) {
        a.x += part[0][t][0] + part[1][t][0];
        a.y += part[0][t][1] + part[1][t][1];
        a.z += part[0][t][2] + part[1][t][2];
        a.w += part[0][t][3] + part[1][t][3];
        float rv[4] = {a.x * inv, a.y * inv, a.z * inv, a.w * inv};
        _Float16 hi4[4], lo4[4];
        #pragma unroll
        for (int q = 0; q < 4; ++q) {
            _Float16 hi = (_Float16)rv[q];
            hi4[q] = hi;
            lo4[q] = (_Float16)(rv[q] - (float)hi);
        }
        *(float2*)(outh + (size_t)i * KP1 + c) = *(float2*)hi4;
        *(float2*)(outl + (size_t)i * KP1 + c) = *(float2*)lo4;
    }
}

// ---------------- layer-2 aggregate over fp16 emb1, f16x8 (16B/lane) gathers ----------------
// 2 edge-groups x 128 lanes (8 f16 cols each), 4-deep unroll -> deep MLP on
// the latency-bound gather stream. Accumulate fp32; hi/lo fp16 planes out.

__global__ __launch_bounds__(256) void aggregate_d(
        const _Float16* __restrict__ h, const float* __restrict__ hs,
        const float* __restrict__ hd, const int* __restrict__ offs,
        const int* __restrict__ ssrc, _Float16* __restrict__ outh,
        _Float16* __restrict__ outl) {
    int i = blockIdx.x;
    int t = threadIdx.x;
    int lane = t & 63;
    int wv = t >> 6;
    int start = offs[i], end = offs[i + 1];
    __shared__ float red[8];
    __shared__ float part[128][8];
    float hdi = hd[i];

    float lmax = -INFINITY;
    for (int p = start + t; p < end; p += 256) {
        float s = hs[ssrc[p]] + hdi;
        s = (s >= 0.f) ? s : s * NEG_SLOPE;
        lmax = fmaxf(lmax, s);
    }
    #pragma unroll
    for (int o = 32; o; o >>= 1) lmax = fmaxf(lmax, __shfl_xor(lmax, o));
    if (lane == 0) red[wv] = lmax;
    __syncthreads();
    float m = fmaxf(fmaxf(red[0], red[1]), fmaxf(red[2], red[3]));

    float lsum = 0.f;
    for (int p = start + t; p < end; p += 256) {
        float s = hs[ssrc[p]] + hdi;
        s = (s >= 0.f) ? s : s * NEG_SLOPE;
        lsum += __expf(s - m);
    }
    #pragma unroll
    for (int o = 32; o; o >>= 1) lsum += __shfl_xor(lsum, o);
    if (lane == 0) red[4 + wv] = lsum;
    __syncthreads();
    float inv = 1.0f / (red[4] + red[5] + red[6] + red[7]);

    int g = t >> 7;            // edge-group 0/1
    int s = t & 127;           // 128 col-slots x 8 f16
    int c = s * 8;
    float a0[8] = {}, a1[8] = {}, a2[8] = {}, a3[8] = {};
    int p = start + g;
    for (; p + 6 < end; p += 8) {
        int j0 = ssrc[p], j1 = ssrc[p + 2], j2 = ssrc[p + 4], j3 = ssrc[p + 6];
        float s0 = hs[j0] + hdi; s0 = (s0 >= 0.f) ? s0 : s0 * NEG_SLOPE;
        float s1 = hs[j1] + hdi; s1 = (s1 >= 0.f) ? s1 : s1 * NEG_SLOPE;
        float s2 = hs[j2] + hdi; s2 = (s2 >= 0.f) ? s2 : s2 * NEG_SLOPE;
        float s3 = hs[j3] + hdi; s3 = (s3 >= 0.f) ? s3 : s3 * NEG_SLOPE;
        float w0 = __expf(s0 - m), w1 = __expf(s1 - m);
        float w2 = __expf(s2 - m), w3 = __expf(s3 - m);
        f16x8 v0 = *(const f16x8*)(h + (size_t)j0 * D + c);
        f16x8 v1 = *(const f16x8*)(h + (size_t)j1 * D + c);
        f16x8 v2 = *(const f16x8*)(h + (size_t)j2 * D + c);
        f16x8 v3 = *(const f16x8*)(h + (size_t)j3 * D + c);
        #pragma unroll
        for (int q = 0; q < 8; ++q) {
            a0[q] += w0 * (float)v0[q];
            a1[q] += w1 * (float)v1[q];
            a2[q] += w2 * (float)v2[q];
            a3[q] += w3 * (float)v3[q];
        }
    }
    for (; p < end; p += 2) {
        int j0 = ssrc[p];
        float s0 = hs[j0] + hdi; s0 = (s0 >= 0.f) ? s0 : s0 * NEG_SLOPE;
        float w0 = __expf(s0 - m);
        f16x8 v0 = *(const f16x8*)(h + (size_t)j0 * D + c);
        #pragma unroll
        for (int q = 0; q < 8; ++q) a0[q] += w0 * (float)v0[q];
    }
    float af[8];
    #pragma unroll
    for (int q = 0; q < 8; ++q) af[q] = (a0[q] + a1[q]) + (a2[q] + a3[q]);
    if (g == 1) {
        #pragma unroll
        for (int q = 0; q < 8; ++q) part[s][q] = af[q];
    }
    __syncthreads();
    if (t < 128) {
        _Float16 hi8[8], lo8[8];
        #pragma unroll
        for (int q = 0; q < 8; ++q) {
            float rv = (af[q] + part[t][q]) * inv;
            _Float16 hi = (_Float16)rv;
            hi8[q] = hi;
            lo8[q] = (_Float16)(rv - (float)hi);
        }
        *(float4*)(outh + (size_t)i * KP2 + c) = *(float4*)hi8;
        *(float4*)(outl + (size_t)i * KP2 + c) = *(float4*)lo8;
    }
}

// ---------------- split-fp16 MFMA GEMM, 2-phase double-buffered, BK=32 ----------------

__global__ __launch_bounds__(256) void gemm_split_mfma(
        const _Float16* __restrict__ Ah, const _Float16* __restrict__ Al,
        const _Float16* __restrict__ BTh,
        float* __restrict__ Cf, _Float16* __restrict__ Ch,
        const float* __restrict__ bias,
        const float* __restrict__ asrc, const float* __restrict__ adst,
        float* __restrict__ hs, float* __restrict__ hd,
        int Mreal, int Kp, int dots) {
    __shared__ char lds[49152];              // 2 x {Ah 8K | Al 8K | Bh 8K}
    const int t    = threadIdx.x;
    const int lane = t & 63;
    const int wid  = t >> 6;
    const int chunkg = (int)gridDim.x >> 3;
    const int vid  = ((int)blockIdx.x & 7) * chunkg + ((int)blockIdx.x >> 3);
    const int n0 = (vid & 7) * 128;
    const int m0 = (vid >> 3) * 128;
    const int wr = (wid >> 1) * 64;
    const int wc = (wid & 1) * 64;
    const int fr = lane & 15;
    const int kg = lane >> 4;

    const int r0 = t >> 2, s0 = t & 3;
    const int r1 = r0 + 64;
    const int g0 = (s0 ^ ((r0 >> 1) & 3)) << 3;
    const int g1 = (s0 ^ ((r1 >> 1) & 3)) << 3;
    const size_t oA0 = (size_t)(m0 + r0) * Kp + g0;
    const size_t oA1 = (size_t)(m0 + r1) * Kp + g1;
    const size_t oB0 = (size_t)(n0 + r0) * Kp + g0;
    const size_t oB1 = (size_t)(n0 + r1) * Kp + g1;
    const int ko = (kg ^ ((fr >> 1) & 3)) << 4;

    f32x4 acc[4][4] = {};

    auto STAGE = [&](int b, int kb) {
        char* base = lds + b * 24576;
        GLOAD_LDS16(Ah  + oA0 + kb, base + t * 16);
        GLOAD_LDS16(Ah  + oA1 + kb, base + 4096  + t * 16);
        GLOAD_LDS16(Al  + oA0 + kb, base + 8192  + t * 16);
        GLOAD_LDS16(Al  + oA1 + kb, base + 12288 + t * 16);
        GLOAD_LDS16(BTh + oB0 + kb, base + 16384 + t * 16);
        GLOAD_LDS16(BTh + oB1 + kb, base + 20480 + t * 16);
    };

    STAGE(0, 0);
    __syncthreads();

    int cur = 0;
    for (int kb = 0; kb < Kp; kb += 32) {
        if (kb + 32 < Kp) STAGE(cur ^ 1, kb + 32);   // prefetch overlaps compute
        char* base = lds + cur * 24576;
        f16x8 ah[4], al[4], bh[4];
        #pragma unroll
        for (int f = 0; f < 4; ++f) {
            int ra = (wr + f * 16 + fr) * 64 + ko;
            int rb = (wc + f * 16 + fr) * 64 + ko;
            ah[f] = *(const f16x8*)(base + ra);
            al[f] = *(const f16x8*)(base + 8192 + ra);
            bh[f] = *(const f16x8*)(base + 16384 + rb);
        }
        #pragma unroll
        for (int fm = 0; fm < 4; ++fm)
            #pragma unroll
            for (int fn = 0; fn < 4; ++fn)
                acc[fm][fn] = __builtin_amdgcn_mfma_f32_16x16x32_f16(
                    ah[fm], bh[fn], acc[fm][fn], 0, 0, 0);
        #pragma unroll
        for (int fm = 0; fm < 4; ++fm)
            #pragma unroll
            for (int fn = 0; fn < 4; ++fn)
                acc[fm][fn] = __builtin_amdgcn_mfma_f32_16x16x32_f16(
                    al[fm], bh[fn], acc[fm][fn], 0, 0, 0);
        __syncthreads();   // drains prefetch + syncs reads of buf cur
        cur ^= 1;
    }

    // epilogue: bias + relu; write fp32 (Cf) or fp16 (Ch)
    float bv[4];
    #pragma unroll
    for (int fn = 0; fn < 4; ++fn) bv[fn] = bias[n0 + wc + fn * 16 + fr];
    #pragma unroll
    for (int fm = 0; fm < 4; ++fm) {
        int mb = m0 + wr + fm * 16 + kg * 4;
        #pragma unroll
        for (int fn = 0; fn < 4; ++fn) {
            int cn = n0 + wc + fn * 16 + fr;
            #pragma unroll
            for (int j = 0; j < 4; ++j) {
                float r = fmaxf(acc[fm][fn][j] + bv[fn], 0.f);
                acc[fm][fn][j] = r;
                int m = mb + j;
                if (m < Mreal) {
                    if (Cf) Cf[(size_t)m * 1024 + cn] = r;
                    else    Ch[(size_t)m * 1024 + cn] = (_Float16)r;
                }
            }
        }
    }

    if (dots) {
        float av[4], dv[4];
        #pragma unroll
        for (int fn = 0; fn < 4; ++fn) {
            int cn = n0 + wc + fn * 16 + fr;
            av[fn] = asrc[cn];
            dv[fn] = adst[cn];
        }
        #pragma unroll
        for (int fm = 0; fm < 4; ++fm) {
            #pragma unroll
            for (int j = 0; j < 4; ++j) {
                float v1 = acc[fm][0][j] * av[0] + acc[fm][1][j] * av[1]
                         + acc[fm][2][j] * av[2] + acc[fm][3][j] * av[3];
                float v2 = acc[fm][0][j] * dv[0] + acc[fm][1][j] * dv[1]
                         + acc[fm][2][j] * dv[2] + acc[fm][3][j] * dv[3];
                #pragma unroll
                for (int o = 1; o < 16; o <<= 1) {
                    v1 += __shfl_xor(v1, o);
                    v2 += __shfl_xor(v2, o);
                }
                int m = m0 + wr + fm * 16 + kg * 4 + j;
                if (fr == 0 && m < Mreal) {
                    atomicAdd(&hs[m], v1);
                    atomicAdd(&hd[m], v2);
                }
            }
        }
    }
}

// ---------------- final fc + softmax (fp16 emb input) ----------------

__global__ void fc_softmax(const _Float16* __restrict__ emb, const float* __restrict__ fcw,
                           const float* __restrict__ fcb, float* __restrict__ out) {
    int wid  = (int)((blockIdx.x * blockDim.x + threadIdx.x) >> 6);
    int lane = threadIdx.x & 63;
    if (wid >= N_NODES) return;
    float acc[N_CLS] = {};
    const _Float16* row = emb + (size_t)wid * D;
    for (int k = lane * 8; k < D; k += 512) {
        f16x8 v = *(const f16x8*)(row + k);
        #pragma unroll
        for (int q = 0; q < 8; ++q) {
            float vv = (float)v[q];
            #pragma unroll
            for (int c = 0; c < N_CLS; ++c) acc[c] += vv * fcw[(k + q) * N_CLS + c];
        }
    }
    #pragma unroll
    for (int c = 0; c < N_CLS; ++c) {
        #pragma unroll
        for (int o = 32; o; o >>= 1) acc[c] += __shfl_xor(acc[c], o);
    }
    if (lane == 0) {
        float logit[N_CLS];
        float m = -INFINITY;
        #pragma unroll
        for (int c = 0; c < N_CLS; ++c) { logit[c] = acc[c] + fcb[c]; m = fmaxf(m, logit[c]); }
        float s = 0.f;
        #pragma unroll
        for (int c = 0; c < N_CLS; ++c) { logit[c] = __expf(logit[c] - m); s += logit[c]; }
        float invs = 1.0f / s;
        #pragma unroll
        for (int c = 0; c < N_CLS; ++c) out[(size_t)wid * N_CLS + c] = logit[c] * invs;
    }
}

// ---------------- launch ----------------

extern "C" void kernel_launch(void* const* d_in, const int* in_sizes, int n_in,
                              void* d_out, int out_size, void* d_ws, size_t ws_size,
                              hipStream_t stream) {
    const float* x        = (const float*)d_in[0];
    const int*   ei       = (const int*)d_in[1];
    const float* W1       = (const float*)d_in[2];
    const float* att_src1 = (const float*)d_in[3];
    const float* att_dst1 = (const float*)d_in[4];
    const float* b1       = (const float*)d_in[5];
    const float* W2       = (const float*)d_in[6];
    const float* att_src2 = (const float*)d_in[7];
    const float* att_dst2 = (const float*)d_in[8];
    const float* b2       = (const float*)d_in[9];
    const float* fc_w     = (const float*)d_in[10];
    const float* fc_b     = (const float*)d_in[11];
    float* out = (float*)d_out;

    const int* src = ei;
    const int* dst = ei + N_EDGES;

    char* w = (char*)d_ws;
    #define ALLOC(name, bytes) char* name = w; w += (((size_t)(bytes) + 255) & ~(size_t)255)
    ALLOC(p_emb1h, (size_t)N_NODES * D * 2);           // emb1 fp16 (gather source)
    ALLOC(p_emb2h, (size_t)N_NODES * D * 2);           // emb2 fp16 (fc input)
    ALLOC(p_hs1,   (size_t)N_NODES * 4);
    ALLOC(p_hd1,   (size_t)N_NODES * 4);
    ALLOC(p_hs2,   (size_t)N_NODES * 4);
    ALLOC(p_hd2,   (size_t)N_NODES * 4);
    ALLOC(p_deg,   (size_t)N_NODES * 4);
    ALLOC(p_offs,  (size_t)(N_NODES + 1) * 4);
    ALLOC(p_pos,   (size_t)N_NODES * 4);
    ALLOC(p_ssrc,  (size_t)E_TOT * 4);
    ALLOC(p_u1,    (size_t)F_IN * 4);
    ALLOC(p_v1,    (size_t)F_IN * 4);
    ALLOC(p_u2,    (size_t)D * 4);
    ALLOC(p_v2,    (size_t)D * 4);
    ALLOC(p_as1,   (size_t)2 * MP * KP1 * 2);          // Ah1|Al1 fp16 planes
    ALLOC(p_as2,   (size_t)2 * MP * KP2 * 2);          // Ah2|Al2 fp16 planes
    ALLOC(p_bt1,   (size_t)D * KP1 * 2);               // BT1h fp16
    ALLOC(p_bt2,   (size_t)D * KP2 * 2);               // BT2h fp16
    #undef ALLOC

    _Float16* emb1h = (_Float16*)p_emb1h;
    _Float16* emb2h = (_Float16*)p_emb2h;
    float* hs1  = (float*)p_hs1;
    float* hd1  = (float*)p_hd1;
    float* hs2  = (float*)p_hs2;
    float* hd2  = (float*)p_hd2;
    int*   deg  = (int*)p_deg;
    int*   offs = (int*)p_offs;
    int*   pos  = (int*)p_pos;
    int*   ssrc = (int*)p_ssrc;
    float* u1 = (float*)p_u1; float* v1 = (float*)p_v1;
    float* u2 = (float*)p_u2; float* v2 = (float*)p_v2;
    _Float16* Ah1  = (_Float16*)p_as1;
    _Float16* Al1  = Ah1 + (size_t)MP * KP1;
    _Float16* Ah2  = (_Float16*)p_as2;
    _Float16* Al2  = Ah2 + (size_t)MP * KP2;
    _Float16* BT1h = (_Float16*)p_bt1;
    _Float16* BT2h = (_Float16*)p_bt2;

    // prep (uv, transposes, zeros, deg init) in one zone-dispatched launch
    mega_prep<<<ZONE_A + ZONE_B + ZONE_C + ZONE_D, 256, 0, stream>>>(
        W1, att_src1, att_dst1, W2, att_src2, att_dst2,
        u1, v1, u2, v2, BT1h, BT2h, hs2, hd2,
        (unsigned short*)Ah1, (unsigned short*)Al1,
        (unsigned short*)Ah2, (unsigned short*)Al2, deg);

    // CSR build
    count_edges<<<(N_EDGES + 255) / 256, 256, 0, stream>>>(dst, deg);
    scan_offs<<<1, 1024, 0, stream>>>(deg, offs, pos);
    scatter_edges<<<(E_TOT + 255) / 256, 256, 0, stream>>>(src, dst, pos, ssrc);

    const int gemmGrid = (D / 128) * (MP / 128);   // 632 = 8*79

    // layer 1: scores, aggregate x, GEMM -> fp16 emb1 (+b1, relu, fused layer-2 dots)
    node_scores_x<<<(N_NODES * 64 + 255) / 256, 256, 0, stream>>>(x, u1, v1, hs1, hd1);
    aggregate_x<<<N_NODES, 256, 0, stream>>>(x, hs1, hd1, offs, ssrc, Ah1, Al1);
    gemm_split_mfma<<<gemmGrid, 256, 0, stream>>>(Ah1, Al1, BT1h,
                                                  (float*)nullptr, emb1h, b1,
                                                  u2, v2, hs2, hd2, N_NODES, KP1, 1);

    // layer 2: aggregate fp16 emb1, GEMM -> fp16 emb2 (+b2, relu)
    aggregate_d<<<N_NODES, 256, 0, stream>>>(emb1h, hs2, hd2, offs, ssrc, Ah2, Al2);
    gemm_split_mfma<<<gemmGrid, 256, 0, stream>>>(Ah2, Al2, BT2h,
                                                  (float*)nullptr, emb2h, b2,
                                                  (const float*)nullptr, (const float*)nullptr,
                                                  (float*)nullptr, (float*)nullptr,
                                                  N_NODES, KP2, 0);

    // classifier
    fc_softmax<<<(N_NODES * 64 + 255) / 256, 256, 0, stream>>>(emb2h, fc_w, fc_b, out);
}